// Round 1
// baseline (22285.995 us; speedup 1.0000x reference)
//
#include <hip/hip_runtime.h>
#include <math.h>

#define B_ 32
#define T_ 48
#define ENC_ 1024
#define PRED_ 320
#define G4P (4*PRED_)        // 1280
#define JH_ 512
#define NJ_ (ENC_+PRED_)     // 1344
#define VOCAB_ 29
#define BLANK_ 28
#define MAXSYM_ 6
#define NSTEPS_ (T_*MAXSYM_) // 288
#define GDEC 80
#define BDEC 512

// ---- workspace layout (indices in floats) ----
#define FPRE_OFF 0                        // B*T*JH = 786432 floats
#define WE_OFF   (FPRE_OFF + B_*T_*JH_)   // 28*1280 = 35840
#define WT_OFF   (WE_OFF + 28*G4P)        // Wj1g transposed: 320*512 = 163840
#define X_OFF    (WT_OFF + PRED_*JH_)     // state dbl-buf: 2*4*320*32 = 81920
#define JG_OFF   (X_OFF + 2*4*PRED_*B_)   // 32*512 = 16384
#define INT_OFF  (JG_OFF + B_*JH_)        // int region (indices into (int*)ws)
#define LAST_I (INT_OFF + 0)
#define TI_I   (INT_OFF + 32)
#define SA_I   (INT_OFF + 64)
#define NB_I   (INT_OFF + 96)
#define ACT_I  (INT_OFF + 128)
#define SEL_I  (INT_OFF + 160)
#define NACT_I (INT_OFF + 192)
#define CNT_I  (INT_OFF + 256)
#define GEN_I  (INT_OFF + 320)

// state element: X[sel][arr][k][b], arr: 0=h0 1=c0 2=h1 3=c1 (k-major for coalescing)
#define XI(s,a,k,bb) ((((s)*4+(a))*PRED_ + (k))*B_ + (bb))

__device__ __forceinline__ float sigm(float v) { return 1.0f / (1.0f + expf(-v)); }

// ---------------- init ----------------
__global__ void k_init(float* __restrict__ ws, int* __restrict__ out) {
    int idx = blockIdx.x * blockDim.x + threadIdx.x;
    int stride = gridDim.x * blockDim.x;
    int* wi = (int*)ws;
    for (int i = idx; i < 2*4*PRED_*B_; i += stride) ws[X_OFF + i] = 0.0f;
    for (int i = idx; i < B_*NSTEPS_; i += stride) out[i] = -1;   // lt
    if (idx < B_) {
        out[B_*NSTEPS_ + idx] = 0;  // lc
        wi[LAST_I + idx] = -1;
        wi[TI_I + idx] = 0;
        wi[SA_I + idx] = 0;
        wi[NB_I + idx] = 1;
        wi[ACT_I + idx] = 1;
        wi[SEL_I + idx] = 0;
    }
    if (idx == 0) { wi[NACT_I] = B_; wi[CNT_I] = 0; wi[GEN_I] = 0; }
}

// ---------------- WE = emb @ Wi0^T  (28 x 1280) ----------------
__global__ __launch_bounds__(256) void k_we(const float* __restrict__ emb,
                                            const float* __restrict__ Wi0,
                                            float* __restrict__ ws) {
    __shared__ float es[PRED_];
    int l = blockIdx.x / 5;        // 28 labels
    int rq = blockIdx.x % 5;       // 5 * 256 = 1280 rows
    int t = threadIdx.x;
    if (t < PRED_) es[t] = emb[l*PRED_ + t];
    if (t + 256 < PRED_) es[t + 256] = emb[l*PRED_ + t + 256];
    __syncthreads();
    int r = rq*256 + t;
    const float4* wr = (const float4*)(Wi0 + (size_t)r*PRED_);
    float acc = 0.0f;
    #pragma unroll 4
    for (int k4 = 0; k4 < PRED_/4; ++k4) {
        float4 w = wr[k4];
        acc += w.x*es[4*k4] + w.y*es[4*k4+1] + w.z*es[4*k4+2] + w.w*es[4*k4+3];
    }
    ws[WE_OFF + l*G4P + r] = acc;
}

// ---------------- Wj1g transpose: WT[k][j] = Wj1[j][1024+k] ----------------
__global__ void k_tr(const float* __restrict__ Wj1, float* __restrict__ ws) {
    int idx = blockIdx.x * blockDim.x + threadIdx.x;
    if (idx < PRED_*JH_) {
        int k = idx / JH_, j = idx % JH_;
        ws[WT_OFF + idx] = Wj1[(size_t)j*NJ_ + ENC_ + k];
    }
}

// ---------------- Fpre[b][t][j] = x[b,t]·Wj1[j,:1024] + bj1[j] ----------------
__global__ __launch_bounds__(256) void k_fpre(const float* __restrict__ x,
                                              const float* __restrict__ Wj1,
                                              const float* __restrict__ bj1,
                                              float* __restrict__ ws) {
    __shared__ float As[B_][129];   // 32 x 128 chunk (+pad)
    __shared__ float Bs[64][129];   // 64 j x 128 chunk (+pad)
    int tt = blockIdx.x >> 3;       // 48 timesteps
    int jb = blockIdx.x & 7;        // 8 j-blocks of 64
    int tid = threadIdx.x;
    int b = tid >> 3, jq = tid & 7;
    float acc[8] = {0,0,0,0,0,0,0,0};
    for (int kc = 0; kc < ENC_; kc += 128) {
        for (int i = tid; i < B_*128; i += 256) {
            int bb = i >> 7, kk = i & 127;
            As[bb][kk] = x[((size_t)bb*T_ + tt)*ENC_ + kc + kk];
        }
        for (int i = tid; i < 64*128; i += 256) {
            int jj = i >> 7, kk = i & 127;
            Bs[jj][kk] = Wj1[((size_t)(jb*64 + jj))*NJ_ + kc + kk];
        }
        __syncthreads();
        for (int kk = 0; kk < 128; ++kk) {
            float a = As[b][kk];
            #pragma unroll
            for (int u = 0; u < 8; ++u) acc[u] += a * Bs[jq*8 + u][kk];
        }
        __syncthreads();
    }
    #pragma unroll
    for (int u = 0; u < 8; ++u) {
        int j = jb*64 + jq*8 + u;
        ws[FPRE_OFF + ((size_t)b*T_ + tt)*JH_ + j] = acc[u] + bj1[j];
    }
}

// ---------------- grid barrier ----------------
__device__ __forceinline__ void grid_bar(int* cnt, int* gen) {
    __syncthreads();
    if (threadIdx.x == 0) {
        __threadfence();
        int g = __hip_atomic_load(gen, __ATOMIC_RELAXED, __HIP_MEMORY_SCOPE_AGENT);
        int a = __hip_atomic_fetch_add(cnt, 1, __ATOMIC_ACQ_REL, __HIP_MEMORY_SCOPE_AGENT);
        if (a == GDEC - 1) {
            __hip_atomic_store(cnt, 0, __ATOMIC_RELAXED, __HIP_MEMORY_SCOPE_AGENT);
            __hip_atomic_store(gen, g + 1, __ATOMIC_RELEASE, __HIP_MEMORY_SCOPE_AGENT);
        } else {
            while (__hip_atomic_load(gen, __ATOMIC_ACQUIRE, __HIP_MEMORY_SCOPE_AGENT) == g)
                __builtin_amdgcn_s_sleep(1);
        }
        __threadfence();
    }
    __syncthreads();
}

// ---------------- persistent decode ----------------
__global__ __launch_bounds__(BDEC) void k_decode(
    const int* __restrict__ out_lens,
    const float* __restrict__ Wh0, const float* __restrict__ b0,
    const float* __restrict__ Wi1, const float* __restrict__ Wh1,
    const float* __restrict__ b1,
    const float* __restrict__ Wj2, const float* __restrict__ bj2,
    float* __restrict__ ws, int* __restrict__ out)
{
    float* Xb = ws + X_OFF;
    float* JG = ws + JG_OFF;
    const float* WE = ws + WE_OFF;
    const float* WT = ws + WT_OFF;
    const float* FP = ws + FPRE_OFF;
    int* wi = (int*)ws;
    int* cnt = wi + CNT_I;
    int* gen = wi + GEN_I;

    const int tid = threadIdx.x;
    const int blk = blockIdx.x;

    __shared__ float wb[32][PRED_];          // weight rows (S1 uses 16, S2 uses 32)
    __shared__ float parts[4][4][4][B_];     // [gate][ks][jl][b]
    __shared__ float gvec[PRED_];
    __shared__ float hid[JH_];
    __shared__ float lpart[VOCAB_][16];
    __shared__ float lg[VOCAB_];
    __shared__ int s_nb[B_], s_sel[B_], s_last[B_];
    __shared__ int s_any, s_exit, s_misc[2];

    const int b  = tid & 31;
    const int jl = (tid >> 5) & 3;
    const int ks = tid >> 7;       // 0..3, K-chunk of 80
    const int j0 = blk * 4;        // 80 blocks x 4 j = 320

    for (int step = 0; step < NSTEPS_; ++step) {
        // ---- load per-b flags (written by previous step's S34, fenced by barrier)
        if (tid < B_) {
            s_nb[tid]   = wi[NB_I + tid];
            s_sel[tid]  = wi[SEL_I + tid];
            s_last[tid] = wi[LAST_I + tid];
        }
        __syncthreads();
        if (tid == 0) {
            int a = 0;
            for (int q = 0; q < B_; ++q) a |= s_nb[q];
            s_any = a;
        }
        __syncthreads();

        if (s_any) {
            // ================= S1: LSTM0 candidates =================
            for (int i = tid; i < 16*PRED_; i += BDEC) {
                int rr = i / PRED_, c = i % PRED_;
                int gate = rr >> 2, jjl = rr & 3;
                wb[rr][c] = Wh0[((size_t)(gate*PRED_ + j0 + jjl))*PRED_ + c];
            }
            __syncthreads();
            if (s_nb[b]) {
                int s = s_sel[b];
                const float* hp = Xb + XI(s,0,0,b);
                const float* w0 = wb[0*4 + jl];
                const float* w1 = wb[1*4 + jl];
                const float* w2 = wb[2*4 + jl];
                const float* w3 = wb[3*4 + jl];
                int k0 = ks * 80;
                float a0=0.f, a1=0.f, a2=0.f, a3=0.f;
                #pragma unroll 4
                for (int kk = k0; kk < k0 + 80; ++kk) {
                    float a = hp[kk*B_];
                    a0 += w0[kk]*a; a1 += w1[kk]*a; a2 += w2[kk]*a; a3 += w3[kk]*a;
                }
                parts[0][ks][jl][b] = a0; parts[1][ks][jl][b] = a1;
                parts[2][ks][jl][b] = a2; parts[3][ks][jl][b] = a3;
            }
            __syncthreads();
            if (tid < 128) {
                int bb = tid & 31, jj = tid >> 5;
                if (s_nb[bb]) {
                    int j = j0 + jj, s = s_sel[bb], ls = s_last[bb];
                    float gt[4];
                    #pragma unroll
                    for (int g4 = 0; g4 < 4; ++g4) {
                        float v = parts[g4][0][jj][bb] + parts[g4][1][jj][bb]
                                + parts[g4][2][jj][bb] + parts[g4][3][jj][bb];
                        v += b0[g4*PRED_ + j];
                        if (ls >= 0) v += WE[(size_t)ls*G4P + g4*PRED_ + j];
                        gt[g4] = v;
                    }
                    float cold = Xb[XI(s,1,j,bb)];
                    float cn = sigm(gt[1])*cold + sigm(gt[0])*tanhf(gt[2]);
                    float hn = sigm(gt[3])*tanhf(cn);
                    Xb[XI(s^1,0,j,bb)] = hn;
                    Xb[XI(s^1,1,j,bb)] = cn;
                }
            }
            grid_bar(cnt, gen);

            // ================= S2: LSTM1 candidates (g) =================
            for (int i = tid; i < 32*PRED_; i += BDEC) {
                int rr = i / PRED_, c = i % PRED_;
                int mat = rr >> 4, gate = (rr >> 2) & 3, jjl = rr & 3;
                const float* W = mat ? Wh1 : Wi1;
                wb[rr][c] = W[((size_t)(gate*PRED_ + j0 + jjl))*PRED_ + c];
            }
            __syncthreads();
            if (s_nb[b]) {
                int s = s_sel[b];
                const float* hx = Xb + XI(s^1,0,0,b);   // h0 candidate (input)
                const float* hh = Xb + XI(s,2,0,b);     // h1 current
                const float* wi0r = wb[0*4 + jl];
                const float* wi1r = wb[1*4 + jl];
                const float* wi2r = wb[2*4 + jl];
                const float* wi3r = wb[3*4 + jl];
                const float* wh0r = wb[16 + 0*4 + jl];
                const float* wh1r = wb[16 + 1*4 + jl];
                const float* wh2r = wb[16 + 2*4 + jl];
                const float* wh3r = wb[16 + 3*4 + jl];
                int k0 = ks * 80;
                float a0=0.f, a1=0.f, a2=0.f, a3=0.f;
                #pragma unroll 4
                for (int kk = k0; kk < k0 + 80; ++kk) {
                    float ax = hx[kk*B_];
                    float ah = hh[kk*B_];
                    a0 += wi0r[kk]*ax + wh0r[kk]*ah;
                    a1 += wi1r[kk]*ax + wh1r[kk]*ah;
                    a2 += wi2r[kk]*ax + wh2r[kk]*ah;
                    a3 += wi3r[kk]*ax + wh3r[kk]*ah;
                }
                parts[0][ks][jl][b] = a0; parts[1][ks][jl][b] = a1;
                parts[2][ks][jl][b] = a2; parts[3][ks][jl][b] = a3;
            }
            __syncthreads();
            if (tid < 128) {
                int bb = tid & 31, jj = tid >> 5;
                if (s_nb[bb]) {
                    int j = j0 + jj, s = s_sel[bb];
                    float gt[4];
                    #pragma unroll
                    for (int g4 = 0; g4 < 4; ++g4) {
                        float v = parts[g4][0][jj][bb] + parts[g4][1][jj][bb]
                                + parts[g4][2][jj][bb] + parts[g4][3][jj][bb];
                        v += b1[g4*PRED_ + j];
                        gt[g4] = v;
                    }
                    float cold = Xb[XI(s,3,j,bb)];
                    float cn = sigm(gt[1])*cold + sigm(gt[0])*tanhf(gt[2]);
                    float hn = sigm(gt[3])*tanhf(cn);
                    Xb[XI(s^1,2,j,bb)] = hn;
                    Xb[XI(s^1,3,j,bb)] = cn;
                }
            }
            grid_bar(cnt, gen);
        }

        // ================= S34: joint + argmax + state update (block per b) =====
        if (blk < B_) {
            const int bb = blk;
            if (tid == 0) { s_misc[0] = wi[ACT_I + bb]; s_misc[1] = wi[TI_I + bb]; }
            __syncthreads();
            if (s_misc[0]) {
                const int nbv = s_nb[bb];
                const int s = s_sel[bb];
                const int tmin = min(s_misc[1], T_ - 1);
                float jgv;
                if (nbv) {
                    if (tid < PRED_) gvec[tid] = Xb[XI(s^1,2,tid,bb)];
                    __syncthreads();
                    float acc = 0.0f;
                    #pragma unroll 4
                    for (int k = 0; k < PRED_; ++k) acc += WT[(size_t)k*JH_ + tid] * gvec[k];
                    JG[(size_t)bb*JH_ + tid] = acc;
                    jgv = acc;
                } else {
                    jgv = JG[(size_t)bb*JH_ + tid];
                }
                float hv = FP[((size_t)bb*T_ + tmin)*JH_ + tid] + jgv;
                hid[tid] = fmaxf(hv, 0.0f);
                __syncthreads();
                {
                    int p = tid >> 5, l = tid & 31;
                    if (l < VOCAB_) {
                        float acc = 0.0f;
                        const float* wr = Wj2 + (size_t)l*JH_ + p*32;
                        const float* hr = &hid[p*32];
                        #pragma unroll 8
                        for (int kk = 0; kk < 32; ++kk) acc += wr[kk] * hr[kk];
                        lpart[l][p] = acc;
                    }
                }
                __syncthreads();
                if (tid < VOCAB_) {
                    float v = bj2[tid];
                    #pragma unroll
                    for (int p = 0; p < 16; ++p) v += lpart[tid][p];
                    lg[tid] = v;
                }
                __syncthreads();
                if (tid == 0) {
                    float best = lg[0]; int bi = 0;
                    for (int l = 1; l < VOCAB_; ++l)
                        if (lg[l] > best) { best = lg[l]; bi = l; }   // first-max ties
                    const int blankness = (bi == BLANK_) ? 1 : 0;
                    int tiv = s_misc[1] + blankness;
                    if (tiv >= out_lens[bb]) {
                        wi[TI_I + bb] = tiv;
                        wi[NB_I + bb] = 0;
                        wi[ACT_I + bb] = 0;
                        atomicSub(wi + NACT_I, 1);
                    } else {
                        int notb = 1 - blankness;
                        int sav = blankness ? 0 : wi[SA_I + bb];
                        if (notb) {
                            wi[SEL_I + bb] = s ^ 1;
                            int lcn = out[B_*NSTEPS_ + bb] + 1;
                            out[B_*NSTEPS_ + bb] = lcn;
                            if (lcn < NSTEPS_) out[bb*NSTEPS_ + lcn] = bi;  // lt[-1]+k+1 = k
                            wi[LAST_I + bb] = bi;
                            sav += 1;
                        }
                        if (sav >= MAXSYM_) { tiv += 1; sav = 0; }
                        wi[TI_I + bb] = tiv;
                        wi[SA_I + bb] = sav;
                        wi[NB_I + bb] = notb;
                    }
                }
            }
        }
        grid_bar(cnt, gen);

        if (tid == 0)
            s_exit = (__hip_atomic_load(wi + NACT_I, __ATOMIC_RELAXED,
                                        __HIP_MEMORY_SCOPE_AGENT) == 0);
        __syncthreads();
        if (s_exit) break;
    }
}

extern "C" void kernel_launch(void* const* d_in, const int* in_sizes, int n_in,
                              void* d_out, int out_size, void* d_ws, size_t ws_size,
                              hipStream_t stream) {
    const float* x    = (const float*)d_in[0];
    const int*   olen = (const int*)d_in[1];
    const float* emb  = (const float*)d_in[2];
    const float* Wi0  = (const float*)d_in[3];
    const float* Wh0  = (const float*)d_in[4];
    const float* b0   = (const float*)d_in[5];
    const float* Wi1  = (const float*)d_in[6];
    const float* Wh1  = (const float*)d_in[7];
    const float* b1   = (const float*)d_in[8];
    const float* Wj1  = (const float*)d_in[9];
    const float* bj1  = (const float*)d_in[10];
    const float* Wj2  = (const float*)d_in[11];
    const float* bj2  = (const float*)d_in[12];
    float* ws = (float*)d_ws;
    int* out = (int*)d_out;

    hipLaunchKernelGGL(k_init, dim3(256), dim3(256), 0, stream, ws, out);
    hipLaunchKernelGGL(k_we,   dim3(28*5), dim3(256), 0, stream, emb, Wi0, ws);
    hipLaunchKernelGGL(k_tr,   dim3((PRED_*JH_ + 255)/256), dim3(256), 0, stream, Wj1, ws);
    hipLaunchKernelGGL(k_fpre, dim3(T_*8), dim3(256), 0, stream, x, Wj1, bj1, ws);
    hipLaunchKernelGGL(k_decode, dim3(GDEC), dim3(BDEC), 0, stream,
                       olen, Wh0, b0, Wi1, Wh1, b1, Wj2, bj2, ws, out);
}

// Round 2
// 16673.520 us; speedup vs baseline: 1.3366x; 1.3366x over previous
//
#include <hip/hip_runtime.h>
#include <math.h>

#define B_ 32
#define T_ 48
#define ENC_ 1024
#define PRED_ 320
#define G4P (4*PRED_)        // 1280
#define JH_ 512
#define NJ_ (ENC_+PRED_)     // 1344
#define VOCAB_ 29
#define BLANK_ 28
#define MAXSYM_ 6
#define NSTEPS_ (T_*MAXSYM_) // 288
#define GDEC 80
#define BDEC 512

// ---- workspace layout (float indices) ----
#define FPRE_OFF 0                         // 786432
#define WE_OFF   (FPRE_OFF + B_*T_*JH_)    // 35840
#define JG_OFF   (WE_OFF + 28*G4P)         // 16384
#define PLOG_OFF (JG_OFF + B_*JH_)         // 64*32*32 = 65536
#define X_OFF    (PLOG_OFF + 64*32*32)     // 81920
#define INT_OFF  (X_OFF + 2*4*PRED_*B_)    // int region
#define LAST_I (INT_OFF + 0)
#define TI_I   (INT_OFF + 32)
#define SA_I   (INT_OFF + 64)
#define NB_I   (INT_OFF + 96)
#define ACT_I  (INT_OFF + 128)
#define SEL_I  (INT_OFF + 160)
#define NACT_I (INT_OFF + 192)
#define CNT_I  (INT_OFF + 256)
#define GEN_I  (INT_OFF + 320)

#define XI(s,a,k,bb) ((((s)*4+(a))*PRED_ + (k))*B_ + (bb))

__device__ __forceinline__ float sigm(float v) { return 1.0f / (1.0f + expf(-v)); }

// ---------------- init ----------------
__global__ void k_init(float* __restrict__ ws, int* __restrict__ out) {
    int idx = blockIdx.x * blockDim.x + threadIdx.x;
    int stride = gridDim.x * blockDim.x;
    int* wi = (int*)ws;
    for (int i = idx; i < 2*4*PRED_*B_; i += stride) ws[X_OFF + i] = 0.0f;
    for (int i = idx; i < B_*NSTEPS_; i += stride) out[i] = -1;   // lt
    if (idx < B_) {
        out[B_*NSTEPS_ + idx] = 0;  // lc
        wi[LAST_I + idx] = -1;
        wi[TI_I + idx] = 0;
        wi[SA_I + idx] = 0;
        wi[NB_I + idx] = 1;
        wi[ACT_I + idx] = 1;
        wi[SEL_I + idx] = 0;
    }
    if (idx == 0) { wi[NACT_I] = B_; wi[CNT_I] = 0; wi[GEN_I] = 0; }
}

// ---------------- WE = emb @ Wi0^T  (28 x 1280) ----------------
__global__ __launch_bounds__(256) void k_we(const float* __restrict__ emb,
                                            const float* __restrict__ Wi0,
                                            float* __restrict__ ws) {
    __shared__ float es[PRED_];
    int l = blockIdx.x / 5;
    int rq = blockIdx.x % 5;
    int t = threadIdx.x;
    if (t < PRED_) es[t] = emb[l*PRED_ + t];
    if (t + 256 < PRED_) es[t + 256] = emb[l*PRED_ + t + 256];
    __syncthreads();
    int r = rq*256 + t;
    const float4* wr = (const float4*)(Wi0 + (size_t)r*PRED_);
    float acc = 0.0f;
    #pragma unroll 4
    for (int k4 = 0; k4 < PRED_/4; ++k4) {
        float4 w = wr[k4];
        acc += w.x*es[4*k4] + w.y*es[4*k4+1] + w.z*es[4*k4+2] + w.w*es[4*k4+3];
    }
    ws[WE_OFF + l*G4P + r] = acc;
}

// ---------------- Fpre[b][t][j] = x[b,t]·Wj1[j,:1024] + bj1[j] ----------------
__global__ __launch_bounds__(256) void k_fpre(const float* __restrict__ x,
                                              const float* __restrict__ Wj1,
                                              const float* __restrict__ bj1,
                                              float* __restrict__ ws) {
    __shared__ float As[B_][129];
    __shared__ float Bs[64][129];
    int tt = blockIdx.x >> 3;
    int jb = blockIdx.x & 7;
    int tid = threadIdx.x;
    int b = tid >> 3, jq = tid & 7;
    float acc[8] = {0,0,0,0,0,0,0,0};
    for (int kc = 0; kc < ENC_; kc += 128) {
        for (int i = tid; i < B_*128; i += 256) {
            int bb = i >> 7, kk = i & 127;
            As[bb][kk] = x[((size_t)bb*T_ + tt)*ENC_ + kc + kk];
        }
        for (int i = tid; i < 64*128; i += 256) {
            int jj = i >> 7, kk = i & 127;
            Bs[jj][kk] = Wj1[((size_t)(jb*64 + jj))*NJ_ + kc + kk];
        }
        __syncthreads();
        for (int kk = 0; kk < 128; ++kk) {
            float a = As[b][kk];
            #pragma unroll
            for (int u = 0; u < 8; ++u) acc[u] += a * Bs[jq*8 + u][kk];
        }
        __syncthreads();
    }
    #pragma unroll
    for (int u = 0; u < 8; ++u) {
        int j = jb*64 + jq*8 + u;
        ws[FPRE_OFF + ((size_t)b*T_ + tt)*JH_ + j] = acc[u] + bj1[j];
    }
}

// ---------------- grid barrier (proven) ----------------
__device__ __forceinline__ void grid_bar(int* cnt, int* gen) {
    __syncthreads();
    if (threadIdx.x == 0) {
        __threadfence();
        int g = __hip_atomic_load(gen, __ATOMIC_RELAXED, __HIP_MEMORY_SCOPE_AGENT);
        int a = __hip_atomic_fetch_add(cnt, 1, __ATOMIC_ACQ_REL, __HIP_MEMORY_SCOPE_AGENT);
        if (a == GDEC - 1) {
            __hip_atomic_store(cnt, 0, __ATOMIC_RELAXED, __HIP_MEMORY_SCOPE_AGENT);
            __hip_atomic_store(gen, g + 1, __ATOMIC_RELEASE, __HIP_MEMORY_SCOPE_AGENT);
        } else {
            while (__hip_atomic_load(gen, __ATOMIC_ACQUIRE, __HIP_MEMORY_SCOPE_AGENT) == g)
                __builtin_amdgcn_s_sleep(1);
        }
        __threadfence();
    }
    __syncthreads();
}

// ---------------- persistent decode ----------------
__global__ __launch_bounds__(BDEC) void k_decode(
    const int* __restrict__ out_lens,
    const float* __restrict__ Wh0, const float* __restrict__ b0,
    const float* __restrict__ Wi1, const float* __restrict__ Wh1,
    const float* __restrict__ b1,
    const float* __restrict__ Wj1,
    const float* __restrict__ Wj2, const float* __restrict__ bj2,
    float* __restrict__ ws, int* __restrict__ out)
{
    float* Xb  = ws + X_OFF;
    float* JGg = ws + JG_OFF;
    float* PL  = ws + PLOG_OFF;
    const float* WE = ws + WE_OFF;
    const float* FP = ws + FPRE_OFF;
    int* wi  = (int*)ws;
    int* cnt = wi + CNT_I;
    int* gen = wi + GEN_I;

    // ---- LDS (all weights resident for the whole kernel) ----
    __shared__ __align__(16) float wh0_s[16][PRED_];   // 20 KB
    __shared__ __align__(16) float wi1_s[16][PRED_];   // 20 KB
    __shared__ __align__(16) float wt_s[8][PRED_];     // 10 KB  (Wj1 g-part, v-major)
    __shared__ float wj2_s[32][8];                     // 1 KB
    __shared__ float we_s[28][16];                     // 1.75 KB
    __shared__ float b0_s[16], b1_s[16];
    __shared__ float scratch[2048 + 64];               // parts / parts3+hid / lred+lg
    __shared__ int s_nb[B_], s_sel[B_], s_last[B_], s_ti[B_], s_act[B_];
    __shared__ int s_any, s_exit;

    const int tid = threadIdx.x;
    const int blk = blockIdx.x;
    const int j0  = blk * 4;

    // ---- one-time preload ----
    for (int i = tid; i < 16*PRED_; i += BDEC) {
        int r = i / PRED_, c = i % PRED_;
        int g = r >> 2, jl = r & 3;
        wh0_s[r][c] = Wh0[((size_t)(g*PRED_ + j0 + jl))*PRED_ + c];
        wi1_s[r][c] = Wi1[((size_t)(g*PRED_ + j0 + jl))*PRED_ + c];
    }
    if (blk < 64) {
        for (int i = tid; i < 8*PRED_; i += BDEC) {
            int v = i / PRED_, k = i % PRED_;
            wt_s[v][k] = Wj1[((size_t)(blk*8 + v))*NJ_ + ENC_ + k];
        }
        for (int i = tid; i < VOCAB_*8; i += BDEC) {
            int l = i >> 3, v = i & 7;
            wj2_s[l][v] = Wj2[(size_t)l*JH_ + blk*8 + v];
        }
    }
    for (int i = tid; i < 28*16; i += BDEC) {
        int ls = i >> 4, r = i & 15;
        int g = r >> 2, jl = r & 3;
        we_s[ls][r] = WE[(size_t)ls*G4P + g*PRED_ + j0 + jl];
    }
    if (tid < 16) {
        int g = tid >> 2, jl = tid & 3;
        b0_s[tid] = b0[g*PRED_ + j0 + jl];
        b1_s[tid] = b1[g*PRED_ + j0 + jl];
    }
    __syncthreads();

    const int b  = tid & 31;
    const int jl = (tid >> 5) & 3;
    const int ks = tid >> 7;       // 0..3
    float* parts = scratch;        // [g][ks][jl][b] = ((g*4+ks)*4+jl)*32+b

    for (int step = 0; step < NSTEPS_; ++step) {
        if (tid < B_) {
            s_nb[tid]   = wi[NB_I + tid];
            s_sel[tid]  = wi[SEL_I + tid];
            s_last[tid] = wi[LAST_I + tid];
            s_ti[tid]   = wi[TI_I + tid];
            s_act[tid]  = wi[ACT_I + tid];
        }
        __syncthreads();
        if (tid == 0) {
            int a = 0;
            for (int q = 0; q < B_; ++q) a |= s_nb[q];
            s_any = a;
        }
        __syncthreads();

        if (s_any) {
            // ================= S1: LSTM0 =================
            if (s_nb[b]) {
                int s = s_sel[b];
                const float* hp = Xb + XI(s,0,0,b);
                int k0 = ks * 80;
                float a0=0.f, a1=0.f, a2=0.f, a3=0.f;
                #pragma unroll 4
                for (int kk = k0; kk < k0 + 80; kk += 4) {
                    float h0v = hp[(kk+0)*B_], h1v = hp[(kk+1)*B_];
                    float h2v = hp[(kk+2)*B_], h3v = hp[(kk+3)*B_];
                    float4 w0 = *(const float4*)&wh0_s[0*4+jl][kk];
                    float4 w1 = *(const float4*)&wh0_s[1*4+jl][kk];
                    float4 w2 = *(const float4*)&wh0_s[2*4+jl][kk];
                    float4 w3 = *(const float4*)&wh0_s[3*4+jl][kk];
                    a0 += w0.x*h0v + w0.y*h1v + w0.z*h2v + w0.w*h3v;
                    a1 += w1.x*h0v + w1.y*h1v + w1.z*h2v + w1.w*h3v;
                    a2 += w2.x*h0v + w2.y*h1v + w2.z*h2v + w2.w*h3v;
                    a3 += w3.x*h0v + w3.y*h1v + w3.z*h2v + w3.w*h3v;
                }
                parts[((0*4+ks)*4+jl)*32+b] = a0;
                parts[((1*4+ks)*4+jl)*32+b] = a1;
                parts[((2*4+ks)*4+jl)*32+b] = a2;
                parts[((3*4+ks)*4+jl)*32+b] = a3;
            }
            __syncthreads();
            if (tid < 128) {
                int bb = tid & 31, jj = tid >> 5;
                if (s_nb[bb]) {
                    int j = j0 + jj, s = s_sel[bb], ls = s_last[bb];
                    float gt[4];
                    #pragma unroll
                    for (int g4 = 0; g4 < 4; ++g4) {
                        float v = parts[((g4*4+0)*4+jj)*32+bb] + parts[((g4*4+1)*4+jj)*32+bb]
                                + parts[((g4*4+2)*4+jj)*32+bb] + parts[((g4*4+3)*4+jj)*32+bb];
                        v += b0_s[g4*4+jj];
                        if (ls >= 0) v += we_s[ls][g4*4+jj];
                        gt[g4] = v;
                    }
                    float cold = Xb[XI(s,1,j,bb)];
                    float cn = sigm(gt[1])*cold + sigm(gt[0])*tanhf(gt[2]);
                    float hn = sigm(gt[3])*tanhf(cn);
                    Xb[XI(s^1,0,j,bb)] = hn;
                    Xb[XI(s^1,1,j,bb)] = cn;
                }
            }
            grid_bar(cnt, gen);

            // ================= S2: LSTM1 =================
            if (s_nb[b]) {
                int s = s_sel[b];
                const float* hx = Xb + XI(s^1,0,0,b);
                const float* hh = Xb + XI(s,2,0,b);
                const float* wh1r0 = Wh1 + ((size_t)(0*PRED_ + j0 + jl))*PRED_;
                const float* wh1r1 = Wh1 + ((size_t)(1*PRED_ + j0 + jl))*PRED_;
                const float* wh1r2 = Wh1 + ((size_t)(2*PRED_ + j0 + jl))*PRED_;
                const float* wh1r3 = Wh1 + ((size_t)(3*PRED_ + j0 + jl))*PRED_;
                int k0 = ks * 80;
                float a0=0.f, a1=0.f, a2=0.f, a3=0.f;
                #pragma unroll 2
                for (int kk = k0; kk < k0 + 80; kk += 4) {
                    float x0 = hx[(kk+0)*B_], x1 = hx[(kk+1)*B_];
                    float x2 = hx[(kk+2)*B_], x3 = hx[(kk+3)*B_];
                    float y0 = hh[(kk+0)*B_], y1 = hh[(kk+1)*B_];
                    float y2 = hh[(kk+2)*B_], y3 = hh[(kk+3)*B_];
                    float4 wa0 = *(const float4*)&wi1_s[0*4+jl][kk];
                    float4 wa1 = *(const float4*)&wi1_s[1*4+jl][kk];
                    float4 wa2 = *(const float4*)&wi1_s[2*4+jl][kk];
                    float4 wa3 = *(const float4*)&wi1_s[3*4+jl][kk];
                    float4 wb0 = *(const float4*)(wh1r0 + kk);
                    float4 wb1 = *(const float4*)(wh1r1 + kk);
                    float4 wb2 = *(const float4*)(wh1r2 + kk);
                    float4 wb3 = *(const float4*)(wh1r3 + kk);
                    a0 += wa0.x*x0+wa0.y*x1+wa0.z*x2+wa0.w*x3 + wb0.x*y0+wb0.y*y1+wb0.z*y2+wb0.w*y3;
                    a1 += wa1.x*x0+wa1.y*x1+wa1.z*x2+wa1.w*x3 + wb1.x*y0+wb1.y*y1+wb1.z*y2+wb1.w*y3;
                    a2 += wa2.x*x0+wa2.y*x1+wa2.z*x2+wa2.w*x3 + wb2.x*y0+wb2.y*y1+wb2.z*y2+wb2.w*y3;
                    a3 += wa3.x*x0+wa3.y*x1+wa3.z*x2+wa3.w*x3 + wb3.x*y0+wb3.y*y1+wb3.z*y2+wb3.w*y3;
                }
                parts[((0*4+ks)*4+jl)*32+b] = a0;
                parts[((1*4+ks)*4+jl)*32+b] = a1;
                parts[((2*4+ks)*4+jl)*32+b] = a2;
                parts[((3*4+ks)*4+jl)*32+b] = a3;
            }
            __syncthreads();
            if (tid < 128) {
                int bb = tid & 31, jj = tid >> 5;
                if (s_nb[bb]) {
                    int j = j0 + jj, s = s_sel[bb];
                    float gt[4];
                    #pragma unroll
                    for (int g4 = 0; g4 < 4; ++g4) {
                        float v = parts[((g4*4+0)*4+jj)*32+bb] + parts[((g4*4+1)*4+jj)*32+bb]
                                + parts[((g4*4+2)*4+jj)*32+bb] + parts[((g4*4+3)*4+jj)*32+bb];
                        v += b1_s[g4*4+jj];
                        gt[g4] = v;
                    }
                    float cold = Xb[XI(s,3,j,bb)];
                    float cn = sigm(gt[1])*cold + sigm(gt[0])*tanhf(gt[2]);
                    float hn = sigm(gt[3])*tanhf(cn);
                    Xb[XI(s^1,2,j,bb)] = hn;
                    Xb[XI(s^1,3,j,bb)] = cn;
                }
            }
            grid_bar(cnt, gen);
        }

        // ================= S3: JG (v-split) + hid + partial logits =================
        if (blk < 64) {
            const int b3 = tid & 31, v3 = (tid >> 5) & 7, ks3 = tid >> 8;  // ks3: 0/1
            float p = 0.f;
            if (s_act[b3] && s_nb[b3]) {
                int s = s_sel[b3];
                const float* h1p = Xb + XI(s^1,2,0,b3);
                int k0 = ks3 * 160;
                #pragma unroll 4
                for (int kk = k0; kk < k0 + 160; kk += 4) {
                    float4 w4 = *(const float4*)&wt_s[v3][kk];
                    p += w4.x*h1p[(kk+0)*B_] + w4.y*h1p[(kk+1)*B_]
                       + w4.z*h1p[(kk+2)*B_] + w4.w*h1p[(kk+3)*B_];
                }
            }
            scratch[ks3*256 + v3*32 + b3] = p;
            __syncthreads();
            if (tid < 256) {
                int bb = tid & 31, vv = tid >> 5;
                if (s_act[bb]) {
                    float jg;
                    int gidx = bb*JH_ + blk*8 + vv;
                    if (s_nb[bb]) {
                        jg = scratch[vv*32+bb] + scratch[256 + vv*32+bb];
                        JGg[gidx] = jg;
                    } else {
                        jg = JGg[gidx];
                    }
                    int tm = min(s_ti[bb], T_ - 1);
                    float hv = FP[((size_t)bb*T_ + tm)*JH_ + blk*8 + vv] + jg;
                    scratch[512 + bb*8 + vv] = fmaxf(hv, 0.f);
                }
            }
            __syncthreads();
            {
                int bb = tid >> 4, lh = tid & 15;
                if (s_act[bb]) {
                    const float* hb = &scratch[512 + bb*8];
                    float h0=hb[0],h1=hb[1],h2=hb[2],h3=hb[3];
                    float h4=hb[4],h5=hb[5],h6=hb[6],h7=hb[7];
                    const float* w = wj2_s[lh];
                    float acc = w[0]*h0+w[1]*h1+w[2]*h2+w[3]*h3+w[4]*h4+w[5]*h5+w[6]*h6+w[7]*h7;
                    PL[((size_t)blk*32 + bb)*32 + lh] = acc;
                    if (lh < 13) {
                        const float* w2 = wj2_s[lh+16];
                        float acc2 = w2[0]*h0+w2[1]*h1+w2[2]*h2+w2[3]*h3+w2[4]*h4+w2[5]*h5+w2[6]*h6+w2[7]*h7;
                        PL[((size_t)blk*32 + bb)*32 + lh + 16] = acc2;
                    }
                }
            }
        }
        grid_bar(cnt, gen);

        // ================= S4: reduce + argmax + state update =================
        if (blk < B_ && s_act[blk]) {
            const int bb = blk;
            int l = tid & 31, kb = tid >> 5;   // kb 0..15
            float acc = 0.f;
            #pragma unroll
            for (int q = 0; q < 4; ++q)
                acc += PL[((size_t)(kb*4+q)*32 + bb)*32 + l];
            scratch[kb*32 + l] = acc;
            __syncthreads();
            if (tid < 32) {
                float v = 0.f;
                #pragma unroll
                for (int p = 0; p < 16; ++p) v += scratch[p*32 + tid];
                v = (tid < VOCAB_) ? (v + bj2[tid]) : -1e30f;
                scratch[512 + tid] = v;
            }
            __syncthreads();
            if (tid == 0) {
                float best = scratch[512]; int bi = 0;
                for (int l2 = 1; l2 < VOCAB_; ++l2) {
                    float vv = scratch[512 + l2];
                    if (vv > best) { best = vv; bi = l2; }
                }
                const int blankness = (bi == BLANK_) ? 1 : 0;
                int tiv = s_ti[bb] + blankness;
                int s = s_sel[bb];
                if (tiv >= out_lens[bb]) {
                    wi[TI_I + bb] = tiv;
                    wi[NB_I + bb] = 0;
                    wi[ACT_I + bb] = 0;
                    atomicSub(wi + NACT_I, 1);
                } else {
                    int notb = 1 - blankness;
                    int sav = blankness ? 0 : wi[SA_I + bb];
                    if (notb) {
                        wi[SEL_I + bb] = s ^ 1;
                        int lcn = out[B_*NSTEPS_ + bb] + 1;
                        out[B_*NSTEPS_ + bb] = lcn;
                        if (lcn < NSTEPS_) out[bb*NSTEPS_ + lcn] = bi;
                        wi[LAST_I + bb] = bi;
                        sav += 1;
                    }
                    if (sav >= MAXSYM_) { tiv += 1; sav = 0; }
                    wi[TI_I + bb] = tiv;
                    wi[SA_I + bb] = sav;
                    wi[NB_I + bb] = notb;
                }
            }
        }
        grid_bar(cnt, gen);

        if (tid == 0)
            s_exit = (__hip_atomic_load(wi + NACT_I, __ATOMIC_RELAXED,
                                        __HIP_MEMORY_SCOPE_AGENT) == 0);
        __syncthreads();
        if (s_exit) break;
    }
}

extern "C" void kernel_launch(void* const* d_in, const int* in_sizes, int n_in,
                              void* d_out, int out_size, void* d_ws, size_t ws_size,
                              hipStream_t stream) {
    const float* x    = (const float*)d_in[0];
    const int*   olen = (const int*)d_in[1];
    const float* emb  = (const float*)d_in[2];
    const float* Wi0  = (const float*)d_in[3];
    const float* Wh0  = (const float*)d_in[4];
    const float* b0   = (const float*)d_in[5];
    const float* Wi1  = (const float*)d_in[6];
    const float* Wh1  = (const float*)d_in[7];
    const float* b1   = (const float*)d_in[8];
    const float* Wj1  = (const float*)d_in[9];
    const float* bj1  = (const float*)d_in[10];
    const float* Wj2  = (const float*)d_in[11];
    const float* bj2  = (const float*)d_in[12];
    float* ws = (float*)d_ws;
    int* out = (int*)d_out;

    hipLaunchKernelGGL(k_init, dim3(256), dim3(256), 0, stream, ws, out);
    hipLaunchKernelGGL(k_we,   dim3(28*5), dim3(256), 0, stream, emb, Wi0, ws);
    hipLaunchKernelGGL(k_fpre, dim3(T_*8), dim3(256), 0, stream, x, Wj1, bj1, ws);
    hipLaunchKernelGGL(k_decode, dim3(GDEC), dim3(BDEC), 0, stream,
                       olen, Wh0, b0, Wi1, Wh1, b1, Wj1, Wj2, bj2, ws, out);
}

// Round 3
// 10835.207 us; speedup vs baseline: 2.0568x; 1.5388x over previous
//
#include <hip/hip_runtime.h>
#include <math.h>

#define B_ 32
#define T_ 48
#define ENC_ 1024
#define PRED_ 320
#define G4P (4*PRED_)        // 1280
#define JH_ 512
#define NJ_ (ENC_+PRED_)     // 1344
#define VOCAB_ 29
#define BLANK_ 28
#define MAXSYM_ 6
#define NSTEPS_ (T_*MAXSYM_) // 288
#define GDEC 80
#define BDEC 512

// ---- workspace layout (float indices) ----
#define FPRE_OFF 0                         // 786432
#define WE_OFF   (FPRE_OFF + B_*T_*JH_)    // 35840
#define JG_OFF   (WE_OFF + 28*G4P)         // 16384
#define LG_OFF   (JG_OFF + B_*JH_)         // 32*32 logit accumulators
#define X_OFF    (LG_OFF + B_*32)          // 81920 state dbl-buf
#define INT_OFF  (X_OFF + 2*4*PRED_*B_)    // int region (indices into (int*)ws)
#define LAST_I (INT_OFF + 0)
#define TI_I   (INT_OFF + 32)
#define SA_I   (INT_OFF + 64)
#define NB_I   (INT_OFF + 96)
#define ACT_I  (INT_OFF + 128)
#define SEL_I  (INT_OFF + 160)
#define NACT_I (INT_OFF + 192)
#define GEN_I  (INT_OFF + 256)
#define DONE_I (INT_OFF + 320)   // 32
#define ARR_I  (INT_OFF + 384)   // 128 (80 used)

#define XI(s,a,k,bb) ((((s)*4+(a))*PRED_ + (k))*B_ + (bb))

__device__ __forceinline__ float sigm(float v) { return 1.0f / (1.0f + expf(-v)); }

// per-access coherent (sc1) ops — bypass non-coherent L2, no cache-wide flushes
__device__ __forceinline__ int  ld_i(const int* p)   { return __hip_atomic_load((int*)p, __ATOMIC_RELAXED, __HIP_MEMORY_SCOPE_AGENT); }
__device__ __forceinline__ void st_i(int* p, int v)  { __hip_atomic_store(p, v, __ATOMIC_RELAXED, __HIP_MEMORY_SCOPE_AGENT); }
__device__ __forceinline__ float ld_f(const float* p){ return __hip_atomic_load((float*)p, __ATOMIC_RELAXED, __HIP_MEMORY_SCOPE_AGENT); }
__device__ __forceinline__ void st_f(float* p, float v){ __hip_atomic_store(p, v, __ATOMIC_RELAXED, __HIP_MEMORY_SCOPE_AGENT); }

// ---------------- init ----------------
__global__ void k_init(float* __restrict__ ws, int* __restrict__ out) {
    int idx = blockIdx.x * blockDim.x + threadIdx.x;
    int stride = gridDim.x * blockDim.x;
    int* wi = (int*)ws;
    for (int i = idx; i < 2*4*PRED_*B_; i += stride) ws[X_OFF + i] = 0.0f;
    for (int i = idx; i < B_*NSTEPS_; i += stride) out[i] = -1;   // lt
    if (idx < B_*32/32*32 && idx < 1024) ws[LG_OFF + idx] = 0.0f; // 32*32
    if (idx < 128) wi[ARR_I + idx] = 0;
    if (idx < 32)  wi[DONE_I + idx] = 0;
    if (idx < B_) {
        out[B_*NSTEPS_ + idx] = 0;  // lc
        wi[LAST_I + idx] = -1;
        wi[TI_I + idx] = 0;
        wi[SA_I + idx] = 0;
        wi[NB_I + idx] = 1;
        wi[ACT_I + idx] = 1;
        wi[SEL_I + idx] = 0;
    }
    if (idx == 0) { wi[NACT_I] = B_; wi[GEN_I] = 0; }
}

// ---------------- WE = emb @ Wi0^T  (28 x 1280) ----------------
__global__ __launch_bounds__(256) void k_we(const float* __restrict__ emb,
                                            const float* __restrict__ Wi0,
                                            float* __restrict__ ws) {
    __shared__ float es[PRED_];
    int l = blockIdx.x / 5;
    int rq = blockIdx.x % 5;
    int t = threadIdx.x;
    if (t < PRED_) es[t] = emb[l*PRED_ + t];
    if (t + 256 < PRED_) es[t + 256] = emb[l*PRED_ + t + 256];
    __syncthreads();
    int r = rq*256 + t;
    const float4* wr = (const float4*)(Wi0 + (size_t)r*PRED_);
    float acc = 0.0f;
    #pragma unroll 4
    for (int k4 = 0; k4 < PRED_/4; ++k4) {
        float4 w = wr[k4];
        acc += w.x*es[4*k4] + w.y*es[4*k4+1] + w.z*es[4*k4+2] + w.w*es[4*k4+3];
    }
    ws[WE_OFF + l*G4P + r] = acc;
}

// ---------------- Fpre[b][t][j] = x[b,t]·Wj1[j,:1024] + bj1[j] ----------------
__global__ __launch_bounds__(256) void k_fpre(const float* __restrict__ x,
                                              const float* __restrict__ Wj1,
                                              const float* __restrict__ bj1,
                                              float* __restrict__ ws) {
    __shared__ float As[B_][129];
    __shared__ float Bs[64][129];
    int tt = blockIdx.x >> 3;
    int jb = blockIdx.x & 7;
    int tid = threadIdx.x;
    int b = tid >> 3, jq = tid & 7;
    float acc[8] = {0,0,0,0,0,0,0,0};
    for (int kc = 0; kc < ENC_; kc += 128) {
        for (int i = tid; i < B_*128; i += 256) {
            int bb = i >> 7, kk = i & 127;
            As[bb][kk] = x[((size_t)bb*T_ + tt)*ENC_ + kc + kk];
        }
        for (int i = tid; i < 64*128; i += 256) {
            int jj = i >> 7, kk = i & 127;
            Bs[jj][kk] = Wj1[((size_t)(jb*64 + jj))*NJ_ + kc + kk];
        }
        __syncthreads();
        for (int kk = 0; kk < 128; ++kk) {
            float a = As[b][kk];
            #pragma unroll
            for (int u = 0; u < 8; ++u) acc[u] += a * Bs[jq*8 + u][kk];
        }
        __syncthreads();
    }
    #pragma unroll
    for (int u = 0; u < 8; ++u) {
        int j = jb*64 + jq*8 + u;
        ws[FPRE_OFF + ((size_t)b*T_ + tt)*JH_ + j] = acc[u] + bj1[j];
    }
}

// ---------------- flag-array grid barrier (no fences, no RMW chain) ----------------
__device__ __forceinline__ void gbar(int* arr, int* gen, int bseq) {
    __syncthreads();   // per-wave s_waitcnt vmcnt(0): sc1 stores are at coherence point
    if (blockIdx.x == 0) {
        if (threadIdx.x < GDEC) {
            if (threadIdx.x == 0) st_i(&arr[0], bseq);
            while (ld_i(&arr[threadIdx.x]) < bseq) __builtin_amdgcn_s_sleep(2);
        }
        __syncthreads();
        if (threadIdx.x == 0) st_i(gen, bseq);
    } else {
        if (threadIdx.x == 0) {
            st_i(&arr[blockIdx.x], bseq);
            while (ld_i(gen) < bseq) __builtin_amdgcn_s_sleep(2);
        }
    }
    __syncthreads();
}

// ---------------- persistent decode ----------------
__global__ __launch_bounds__(BDEC) void k_decode(
    const int* __restrict__ out_lens,
    const float* __restrict__ Wh0, const float* __restrict__ b0,
    const float* __restrict__ Wi1, const float* __restrict__ Wh1,
    const float* __restrict__ b1,
    const float* __restrict__ Wj1,
    const float* __restrict__ Wj2, const float* __restrict__ bj2,
    float* __restrict__ ws, int* __restrict__ out)
{
    float* Xb  = ws + X_OFF;
    float* JGg = ws + JG_OFF;
    float* LG  = ws + LG_OFF;
    const float* WE = ws + WE_OFF;
    const float* FP = ws + FPRE_OFF;
    int* wi   = (int*)ws;
    int* arr  = wi + ARR_I;
    int* gen  = wi + GEN_I;
    int* done = wi + DONE_I;

    __shared__ __align__(16) float wh0_s[16][PRED_];   // 20 KB
    __shared__ __align__(16) float wi1_s[16][PRED_];   // 20 KB
    __shared__ __align__(16) float wt_s[8][PRED_];     // 10 KB (Wj1 g-part, v-major)
    __shared__ float hs0[B_*321];                      // 41 KB staged h (padded)
    __shared__ float hs1[B_*321];                      // 41 KB
    __shared__ float wj2_s[VOCAB_][8];
    __shared__ float we_s[28][16];
    __shared__ float b0_s[16], b1_s[16];
    __shared__ float parts[2048];                      // S1/S2 partials; S3 jg partials
    __shared__ float hid[B_*8];
    __shared__ int s_nb[B_], s_sel[B_], s_last[B_], s_ti[B_], s_act[B_];
    __shared__ int s_any, s_exit;

    const int tid = threadIdx.x;
    const int blk = blockIdx.x;
    const int j0  = blk * 4;

    // ---- one-time preload (read-only, normally cached) ----
    for (int i = tid; i < 16*PRED_; i += BDEC) {
        int r = i / PRED_, c = i % PRED_;
        int g = r >> 2, jl = r & 3;
        wh0_s[r][c] = Wh0[((size_t)(g*PRED_ + j0 + jl))*PRED_ + c];
        wi1_s[r][c] = Wi1[((size_t)(g*PRED_ + j0 + jl))*PRED_ + c];
    }
    if (blk < 64) {
        for (int i = tid; i < 8*PRED_; i += BDEC) {
            int v = i / PRED_, k = i % PRED_;
            wt_s[v][k] = Wj1[((size_t)(blk*8 + v))*NJ_ + ENC_ + k];
        }
        for (int i = tid; i < VOCAB_*8; i += BDEC) {
            int l = i >> 3, v = i & 7;
            wj2_s[l][v] = Wj2[(size_t)l*JH_ + blk*8 + v];
        }
    }
    for (int i = tid; i < 28*16; i += BDEC) {
        int ls = i >> 4, r = i & 15;
        int g = r >> 2, jl = r & 3;
        we_s[ls][r] = WE[(size_t)ls*G4P + g*PRED_ + j0 + jl];
    }
    if (tid < 16) {
        int g = tid >> 2, jl = tid & 3;
        b0_s[tid] = b0[g*PRED_ + j0 + jl];
        b1_s[tid] = b1[g*PRED_ + j0 + jl];
    }
    __syncthreads();

    const int b  = tid & 31;
    const int jl = (tid >> 5) & 3;
    const int ks = tid >> 7;       // 0..3
    int bseq = 1;

    for (int step = 0; step < NSTEPS_; ++step) {
        if (tid < B_) {
            s_nb[tid]   = ld_i(&wi[NB_I + tid]);
            s_sel[tid]  = ld_i(&wi[SEL_I + tid]);
            s_last[tid] = ld_i(&wi[LAST_I + tid]);
            s_ti[tid]   = ld_i(&wi[TI_I + tid]);
            s_act[tid]  = ld_i(&wi[ACT_I + tid]);
        }
        __syncthreads();
        if (tid == 0) {
            int a = 0;
            for (int q = 0; q < B_; ++q) a |= s_nb[q];
            s_any = a;
        }
        __syncthreads();

        if (s_any) {
            // ================= S1: LSTM0 =================
            for (int i = tid; i < B_*PRED_; i += BDEC) {
                int bb = i & 31, kk = i >> 5;
                if (s_nb[bb]) hs0[bb*321 + kk] = ld_f(&Xb[XI(s_sel[bb],0,kk,bb)]);
            }
            __syncthreads();
            if (s_nb[b]) {
                const float* hrow = &hs0[b*321];
                int k0 = ks * 80;
                float a0=0.f, a1=0.f, a2=0.f, a3=0.f;
                #pragma unroll 4
                for (int kk = k0; kk < k0 + 80; kk += 4) {
                    float h0v = hrow[kk+0], h1v = hrow[kk+1];
                    float h2v = hrow[kk+2], h3v = hrow[kk+3];
                    float4 w0 = *(const float4*)&wh0_s[0*4+jl][kk];
                    float4 w1 = *(const float4*)&wh0_s[1*4+jl][kk];
                    float4 w2 = *(const float4*)&wh0_s[2*4+jl][kk];
                    float4 w3 = *(const float4*)&wh0_s[3*4+jl][kk];
                    a0 += w0.x*h0v + w0.y*h1v + w0.z*h2v + w0.w*h3v;
                    a1 += w1.x*h0v + w1.y*h1v + w1.z*h2v + w1.w*h3v;
                    a2 += w2.x*h0v + w2.y*h1v + w2.z*h2v + w2.w*h3v;
                    a3 += w3.x*h0v + w3.y*h1v + w3.z*h2v + w3.w*h3v;
                }
                parts[((0*4+ks)*4+jl)*32+b] = a0;
                parts[((1*4+ks)*4+jl)*32+b] = a1;
                parts[((2*4+ks)*4+jl)*32+b] = a2;
                parts[((3*4+ks)*4+jl)*32+b] = a3;
            }
            __syncthreads();
            if (tid < 128) {
                int bb = tid & 31, jj = tid >> 5;
                if (s_nb[bb]) {
                    int j = j0 + jj, s = s_sel[bb], ls = s_last[bb];
                    float gt[4];
                    #pragma unroll
                    for (int g4 = 0; g4 < 4; ++g4) {
                        float v = parts[((g4*4+0)*4+jj)*32+bb] + parts[((g4*4+1)*4+jj)*32+bb]
                                + parts[((g4*4+2)*4+jj)*32+bb] + parts[((g4*4+3)*4+jj)*32+bb];
                        v += b0_s[g4*4+jj];
                        if (ls >= 0) v += we_s[ls][g4*4+jj];
                        gt[g4] = v;
                    }
                    float cold = ld_f(&Xb[XI(s,1,j,bb)]);
                    float cn = sigm(gt[1])*cold + sigm(gt[0])*tanhf(gt[2]);
                    float hn = sigm(gt[3])*tanhf(cn);
                    st_f(&Xb[XI(s^1,0,j,bb)], hn);
                    st_f(&Xb[XI(s^1,1,j,bb)], cn);
                }
            }
            gbar(arr, gen, bseq); ++bseq;

            // ================= S2: LSTM1 =================
            for (int i = tid; i < B_*PRED_; i += BDEC) {
                int bb = i & 31, kk = i >> 5;
                if (s_nb[bb]) {
                    int s = s_sel[bb];
                    hs0[bb*321 + kk] = ld_f(&Xb[XI(s^1,0,kk,bb)]);   // h0 candidate
                    hs1[bb*321 + kk] = ld_f(&Xb[XI(s,2,kk,bb)]);     // h1 current
                }
            }
            __syncthreads();
            if (s_nb[b]) {
                const float* hxr = &hs0[b*321];
                const float* hhr = &hs1[b*321];
                const float* wh1r0 = Wh1 + ((size_t)(0*PRED_ + j0 + jl))*PRED_;
                const float* wh1r1 = Wh1 + ((size_t)(1*PRED_ + j0 + jl))*PRED_;
                const float* wh1r2 = Wh1 + ((size_t)(2*PRED_ + j0 + jl))*PRED_;
                const float* wh1r3 = Wh1 + ((size_t)(3*PRED_ + j0 + jl))*PRED_;
                int k0 = ks * 80;
                float a0=0.f, a1=0.f, a2=0.f, a3=0.f;
                #pragma unroll 2
                for (int kk = k0; kk < k0 + 80; kk += 4) {
                    float x0 = hxr[kk+0], x1 = hxr[kk+1], x2 = hxr[kk+2], x3 = hxr[kk+3];
                    float y0 = hhr[kk+0], y1 = hhr[kk+1], y2 = hhr[kk+2], y3 = hhr[kk+3];
                    float4 wa0 = *(const float4*)&wi1_s[0*4+jl][kk];
                    float4 wa1 = *(const float4*)&wi1_s[1*4+jl][kk];
                    float4 wa2 = *(const float4*)&wi1_s[2*4+jl][kk];
                    float4 wa3 = *(const float4*)&wi1_s[3*4+jl][kk];
                    float4 wb0 = *(const float4*)(wh1r0 + kk);
                    float4 wb1 = *(const float4*)(wh1r1 + kk);
                    float4 wb2 = *(const float4*)(wh1r2 + kk);
                    float4 wb3 = *(const float4*)(wh1r3 + kk);
                    a0 += wa0.x*x0+wa0.y*x1+wa0.z*x2+wa0.w*x3 + wb0.x*y0+wb0.y*y1+wb0.z*y2+wb0.w*y3;
                    a1 += wa1.x*x0+wa1.y*x1+wa1.z*x2+wa1.w*x3 + wb1.x*y0+wb1.y*y1+wb1.z*y2+wb1.w*y3;
                    a2 += wa2.x*x0+wa2.y*x1+wa2.z*x2+wa2.w*x3 + wb2.x*y0+wb2.y*y1+wb2.z*y2+wb2.w*y3;
                    a3 += wa3.x*x0+wa3.y*x1+wa3.z*x2+wa3.w*x3 + wb3.x*y0+wb3.y*y1+wb3.z*y2+wb3.w*y3;
                }
                parts[((0*4+ks)*4+jl)*32+b] = a0;
                parts[((1*4+ks)*4+jl)*32+b] = a1;
                parts[((2*4+ks)*4+jl)*32+b] = a2;
                parts[((3*4+ks)*4+jl)*32+b] = a3;
            }
            __syncthreads();
            if (tid < 128) {
                int bb = tid & 31, jj = tid >> 5;
                if (s_nb[bb]) {
                    int j = j0 + jj, s = s_sel[bb];
                    float gt[4];
                    #pragma unroll
                    for (int g4 = 0; g4 < 4; ++g4) {
                        float v = parts[((g4*4+0)*4+jj)*32+bb] + parts[((g4*4+1)*4+jj)*32+bb]
                                + parts[((g4*4+2)*4+jj)*32+bb] + parts[((g4*4+3)*4+jj)*32+bb];
                        v += b1_s[g4*4+jj];
                        gt[g4] = v;
                    }
                    float cold = ld_f(&Xb[XI(s,3,j,bb)]);
                    float cn = sigm(gt[1])*cold + sigm(gt[0])*tanhf(gt[2]);
                    float hn = sigm(gt[3])*tanhf(cn);
                    st_f(&Xb[XI(s^1,2,j,bb)], hn);
                    st_f(&Xb[XI(s^1,3,j,bb)], cn);
                }
            }
            gbar(arr, gen, bseq); ++bseq;
        }

        // ===== S3: JG (v-split) + hid + partial logits + per-b finalize =====
        if (blk < 64) {
            for (int i = tid; i < B_*PRED_; i += BDEC) {
                int bb = i & 31, kk = i >> 5;
                if (s_act[bb] && s_nb[bb])
                    hs0[bb*321 + kk] = ld_f(&Xb[XI(s_sel[bb]^1,2,kk,bb)]);  // h1 candidate
            }
            __syncthreads();
            {
                const int b3 = tid & 31, v3 = (tid >> 5) & 7, ks3 = tid >> 8;  // ks3: 0/1
                float p = 0.f;
                if (s_act[b3] && s_nb[b3]) {
                    const float* hrow = &hs0[b3*321];
                    int k0 = ks3 * 160;
                    #pragma unroll 4
                    for (int kk = k0; kk < k0 + 160; kk += 4) {
                        float4 w4 = *(const float4*)&wt_s[v3][kk];
                        p += w4.x*hrow[kk+0] + w4.y*hrow[kk+1]
                           + w4.z*hrow[kk+2] + w4.w*hrow[kk+3];
                    }
                }
                parts[ks3*256 + v3*32 + b3] = p;
            }
            __syncthreads();
            if (tid < 256) {
                int bb = tid & 31, vv = tid >> 5;
                if (s_act[bb]) {
                    float jg;
                    int gidx = bb*JH_ + blk*8 + vv;
                    if (s_nb[bb]) {
                        jg = parts[vv*32+bb] + parts[256 + vv*32+bb];
                        JGg[gidx] = jg;            // block-private: normal store
                    } else {
                        jg = JGg[gidx];
                    }
                    int tm = min(s_ti[bb], T_ - 1);
                    float hv = FP[((size_t)bb*T_ + tm)*JH_ + blk*8 + vv] + jg;
                    hid[bb*8 + vv] = fmaxf(hv, 0.f);
                }
            }
            __syncthreads();
            {
                int bb = tid >> 4, lh = tid & 15;
                if (s_act[bb]) {
                    const float* hb = &hid[bb*8];
                    float h0=hb[0],h1=hb[1],h2=hb[2],h3=hb[3];
                    float h4=hb[4],h5=hb[5],h6=hb[6],h7=hb[7];
                    const float* w = wj2_s[lh];
                    float acc = w[0]*h0+w[1]*h1+w[2]*h2+w[3]*h3+w[4]*h4+w[5]*h5+w[6]*h6+w[7]*h7;
                    atomicAdd(&LG[bb*32 + lh], acc);
                    if (lh < VOCAB_ - 16) {
                        const float* w2 = wj2_s[lh+16];
                        float acc2 = w2[0]*h0+w2[1]*h1+w2[2]*h2+w2[3]*h3+w2[4]*h4+w2[5]*h5+w2[6]*h6+w2[7]*h7;
                        atomicAdd(&LG[bb*32 + lh + 16], acc2);
                    }
                }
            }
            __syncthreads();   // drain this block's atomicAdds (per-wave vmcnt(0))
            if (tid < B_ && s_act[tid]) {
                const int bb = tid;
                int old = atomicAdd(&done[bb], 1);
                if (old == 63) {
                    // all 64 v-blocks' adds are globally applied: finalize batch bb
                    float best = -1e30f; int bi = 0;
                    for (int l = 0; l < VOCAB_; ++l) {
                        float v = ld_f(&LG[bb*32 + l]) + bj2[l];
                        if (v > best) { best = v; bi = l; }
                    }
                    const int blankness = (bi == BLANK_) ? 1 : 0;
                    int tiv = s_ti[bb] + blankness;
                    int s = s_sel[bb];
                    if (tiv >= out_lens[bb]) {
                        st_i(&wi[TI_I + bb], tiv);
                        st_i(&wi[NB_I + bb], 0);
                        st_i(&wi[ACT_I + bb], 0);
                        atomicSub(wi + NACT_I, 1);
                    } else {
                        int notb = 1 - blankness;
                        int sav = blankness ? 0 : ld_i(&wi[SA_I + bb]);
                        if (notb) {
                            st_i(&wi[SEL_I + bb], s ^ 1);
                            int lcn = ld_i(&out[B_*NSTEPS_ + bb]) + 1;
                            st_i(&out[B_*NSTEPS_ + bb], lcn);
                            if (lcn < NSTEPS_) st_i(&out[bb*NSTEPS_ + lcn], bi);
                            st_i(&wi[LAST_I + bb], bi);
                            sav += 1;
                        }
                        if (sav >= MAXSYM_) { tiv += 1; sav = 0; }
                        st_i(&wi[TI_I + bb], tiv);
                        st_i(&wi[SA_I + bb], sav);
                        st_i(&wi[NB_I + bb], notb);
                    }
                    // reset accumulators for next step
                    for (int l = 0; l < VOCAB_; ++l) st_f(&LG[bb*32 + l], 0.f);
                    st_i(&done[bb], 0);
                }
            }
        }
        gbar(arr, gen, bseq); ++bseq;

        if (tid == 0)
            s_exit = (ld_i(wi + NACT_I) == 0);
        __syncthreads();
        if (s_exit) break;
    }
}

extern "C" void kernel_launch(void* const* d_in, const int* in_sizes, int n_in,
                              void* d_out, int out_size, void* d_ws, size_t ws_size,
                              hipStream_t stream) {
    const float* x    = (const float*)d_in[0];
    const int*   olen = (const int*)d_in[1];
    const float* emb  = (const float*)d_in[2];
    const float* Wi0  = (const float*)d_in[3];
    const float* Wh0  = (const float*)d_in[4];
    const float* b0   = (const float*)d_in[5];
    const float* Wi1  = (const float*)d_in[6];
    const float* Wh1  = (const float*)d_in[7];
    const float* b1   = (const float*)d_in[8];
    const float* Wj1  = (const float*)d_in[9];
    const float* bj1  = (const float*)d_in[10];
    const float* Wj2  = (const float*)d_in[11];
    const float* bj2  = (const float*)d_in[12];
    float* ws = (float*)d_ws;
    int* out = (int*)d_out;

    hipLaunchKernelGGL(k_init, dim3(256), dim3(256), 0, stream, ws, out);
    hipLaunchKernelGGL(k_we,   dim3(28*5), dim3(256), 0, stream, emb, Wi0, ws);
    hipLaunchKernelGGL(k_fpre, dim3(T_*8), dim3(256), 0, stream, x, Wj1, bj1, ws);
    hipLaunchKernelGGL(k_decode, dim3(GDEC), dim3(BDEC), 0, stream,
                       olen, Wh0, b0, Wi1, Wh1, b1, Wj1, Wj2, bj2, ws, out);
}

// Round 4
// 10354.967 us; speedup vs baseline: 2.1522x; 1.0464x over previous
//
#include <hip/hip_runtime.h>
#include <math.h>

#define B_ 32
#define T_ 48
#define ENC_ 1024
#define PRED_ 320
#define G4P (4*PRED_)        // 1280
#define JH_ 512
#define NJ_ (ENC_+PRED_)     // 1344
#define VOCAB_ 29
#define BLANK_ 28
#define MAXSYM_ 6
#define NSTEPS_ (T_*MAXSYM_) // 288
#define GDEC 80
#define BDEC 512

// ---- workspace layout (float indices) ----
#define FPRE_OFF 0                         // 786432
#define WE_OFF   (FPRE_OFF + B_*T_*JH_)    // 35840
#define JG_OFF   (WE_OFF + 28*G4P)         // 16384
#define LG_OFF   (JG_OFF + B_*JH_)         // 2 x 32 x 32 logit accumulators (parity)
#define X_OFF    (LG_OFF + 2*B_*32)        // 81920 state dbl-buf
#define INT_OFF  (X_OFF + 2*4*PRED_*B_)    // int region
#define DONE_I (INT_OFF + 0)    // 32 (monotonic)
#define ARR1_I (INT_OFF + 64)   // 128
#define ARR2_I (INT_OFF + 192)  // 128
#define W_I    (INT_OFF + 320)  // 64 ints = 32 u64 packed per-b flag words

// w word layout: [0] nb, [1] act, [10:2] ti, [15:11] last+1, [18:16] sa, [27:19] lc, [63:32] tag
#define XI(s,a,k,bb) ((((s)*4+(a))*PRED_ + (k))*B_ + (bb))

__device__ __forceinline__ float sigm(float v) { return 1.0f / (1.0f + expf(-v)); }

__device__ __forceinline__ int  ld_i(const int* p)   { return __hip_atomic_load((int*)p, __ATOMIC_RELAXED, __HIP_MEMORY_SCOPE_AGENT); }
__device__ __forceinline__ void st_i(int* p, int v)  { __hip_atomic_store(p, v, __ATOMIC_RELAXED, __HIP_MEMORY_SCOPE_AGENT); }
__device__ __forceinline__ float ld_f(const float* p){ return __hip_atomic_load((float*)p, __ATOMIC_RELAXED, __HIP_MEMORY_SCOPE_AGENT); }
__device__ __forceinline__ void st_f(float* p, float v){ __hip_atomic_store(p, v, __ATOMIC_RELAXED, __HIP_MEMORY_SCOPE_AGENT); }
__device__ __forceinline__ unsigned long long ld_u64(const unsigned long long* p){
    return __hip_atomic_load((unsigned long long*)p, __ATOMIC_RELAXED, __HIP_MEMORY_SCOPE_AGENT); }
__device__ __forceinline__ void st_u64(unsigned long long* p, unsigned long long v){
    __hip_atomic_store(p, v, __ATOMIC_RELAXED, __HIP_MEMORY_SCOPE_AGENT); }

// ---------------- init ----------------
__global__ void k_init(float* __restrict__ ws, int* __restrict__ out) {
    int idx = blockIdx.x * blockDim.x + threadIdx.x;
    int stride = gridDim.x * blockDim.x;
    int* wi = (int*)ws;
    for (int i = idx; i < 2*4*PRED_*B_; i += stride) ws[X_OFF + i] = 0.0f;
    for (int i = idx; i < 2*B_*32; i += stride) ws[LG_OFF + i] = 0.0f;
    for (int i = idx; i < B_*NSTEPS_; i += stride) out[i] = -1;   // lt
    if (idx < 128) { wi[ARR1_I + idx] = 0; wi[ARR2_I + idx] = 0; }
    if (idx < 32) {
        wi[DONE_I + idx] = 0;
        ((unsigned long long*)(wi + W_I))[idx] = 3ULL;  // nb=1, act=1, ti=0, last=-1, sa=0, lc=0, tag=0
        out[B_*NSTEPS_ + idx] = 0;  // lc
    }
}

// ---------------- WE = emb @ Wi0^T  (28 x 1280) ----------------
__global__ __launch_bounds__(256) void k_we(const float* __restrict__ emb,
                                            const float* __restrict__ Wi0,
                                            float* __restrict__ ws) {
    __shared__ float es[PRED_];
    int l = blockIdx.x / 5;
    int rq = blockIdx.x % 5;
    int t = threadIdx.x;
    if (t < PRED_) es[t] = emb[l*PRED_ + t];
    if (t + 256 < PRED_) es[t + 256] = emb[l*PRED_ + t + 256];
    __syncthreads();
    int r = rq*256 + t;
    const float4* wr = (const float4*)(Wi0 + (size_t)r*PRED_);
    float acc = 0.0f;
    #pragma unroll 4
    for (int k4 = 0; k4 < PRED_/4; ++k4) {
        float4 w = wr[k4];
        acc += w.x*es[4*k4] + w.y*es[4*k4+1] + w.z*es[4*k4+2] + w.w*es[4*k4+3];
    }
    ws[WE_OFF + l*G4P + r] = acc;
}

// ---------------- Fpre[b][t][j] = x[b,t]·Wj1[j,:1024] + bj1[j] ----------------
__global__ __launch_bounds__(256) void k_fpre(const float* __restrict__ x,
                                              const float* __restrict__ Wj1,
                                              const float* __restrict__ bj1,
                                              float* __restrict__ ws) {
    __shared__ float As[B_][129];
    __shared__ float Bs[64][129];
    int tt = blockIdx.x >> 3;
    int jb = blockIdx.x & 7;
    int tid = threadIdx.x;
    int b = tid >> 3, jq = tid & 7;
    float acc[8] = {0,0,0,0,0,0,0,0};
    for (int kc = 0; kc < ENC_; kc += 128) {
        for (int i = tid; i < B_*128; i += 256) {
            int bb = i >> 7, kk = i & 127;
            As[bb][kk] = x[((size_t)bb*T_ + tt)*ENC_ + kc + kk];
        }
        for (int i = tid; i < 64*128; i += 256) {
            int jj = i >> 7, kk = i & 127;
            Bs[jj][kk] = Wj1[((size_t)(jb*64 + jj))*NJ_ + kc + kk];
        }
        __syncthreads();
        for (int kk = 0; kk < 128; ++kk) {
            float a = As[b][kk];
            #pragma unroll
            for (int u = 0; u < 8; ++u) acc[u] += a * Bs[jq*8 + u][kk];
        }
        __syncthreads();
    }
    #pragma unroll
    for (int u = 0; u < 8; ++u) {
        int j = jb*64 + jq*8 + u;
        ws[FPRE_OFF + ((size_t)b*T_ + tt)*JH_ + j] = acc[u] + bj1[j];
    }
}

// ---------------- persistent decode ----------------
__global__ __launch_bounds__(BDEC) void k_decode(
    const int* __restrict__ out_lens,
    const float* __restrict__ Wh0, const float* __restrict__ b0,
    const float* __restrict__ Wi1, const float* __restrict__ Wh1,
    const float* __restrict__ b1,
    const float* __restrict__ Wj1,
    const float* __restrict__ Wj2, const float* __restrict__ bj2,
    float* __restrict__ ws, int* __restrict__ out)
{
    float* Xb  = ws + X_OFF;
    float* JGg = ws + JG_OFF;
    float* LG  = ws + LG_OFF;
    const float* WE = ws + WE_OFF;
    const float* FP = ws + FPRE_OFF;
    int* wi   = (int*)ws;
    int* done = wi + DONE_I;
    int* arr1 = wi + ARR1_I;
    int* arr2 = wi + ARR2_I;
    unsigned long long* wq = (unsigned long long*)(wi + W_I);

    __shared__ __align__(16) float wh0_s[16][PRED_];   // 20 KB
    __shared__ __align__(16) float wi1_s[16][PRED_];   // 20 KB
    __shared__ __align__(16) float wt_s[8][PRED_];     // 10 KB
    __shared__ float hs0[B_*321];                      // 41 KB
    __shared__ float hs1[B_*321];                      // 41 KB
    __shared__ float cs0[128], cs1[128];
    __shared__ float wj2_s[VOCAB_][8];
    __shared__ float we_s[28][16];
    __shared__ float b0_s[16], b1_s[16];
    __shared__ float parts[2048];
    __shared__ float hid[256];
    __shared__ unsigned long long s_w[32];
    __shared__ int s_ti[32], s_last[32], s_sa[32], s_lc[32], s_cnt[32];
    __shared__ unsigned s_nbm, s_actm;

    const int tid = threadIdx.x;
    const int blk = blockIdx.x;
    const int j0  = blk * 4;

    // ---- one-time preload (read-only, normally cached) ----
    for (int i = tid; i < 16*PRED_; i += BDEC) {
        int r = i / PRED_, c = i % PRED_;
        int g = r >> 2, jl = r & 3;
        wh0_s[r][c] = Wh0[((size_t)(g*PRED_ + j0 + jl))*PRED_ + c];
        wi1_s[r][c] = Wi1[((size_t)(g*PRED_ + j0 + jl))*PRED_ + c];
    }
    if (blk < 64) {
        for (int i = tid; i < 8*PRED_; i += BDEC) {
            int v = i / PRED_, k = i % PRED_;
            wt_s[v][k] = Wj1[((size_t)(blk*8 + v))*NJ_ + ENC_ + k];
        }
        for (int i = tid; i < VOCAB_*8; i += BDEC) {
            int l = i >> 3, v = i & 7;
            wj2_s[l][v] = Wj2[(size_t)l*JH_ + blk*8 + v];
        }
    }
    for (int i = tid; i < 28*16; i += BDEC) {
        int ls = i >> 4, r = i & 15;
        int g = r >> 2, jl = r & 3;
        we_s[ls][r] = WE[(size_t)ls*G4P + g*PRED_ + j0 + jl];
    }
    if (tid < 16) {
        int g = tid >> 2, jl = tid & 3;
        b0_s[tid] = b0[g*PRED_ + j0 + jl];
        b1_s[tid] = b1[g*PRED_ + j0 + jl];
    }
    if (tid < 32) s_cnt[tid] = 0;
    __syncthreads();

    const int b  = tid & 31;
    const int jl = (tid >> 5) & 3;
    const int ks = tid >> 7;       // 0..3
    unsigned sel_mask = 0;

    for (int s = 0; s < NSTEPS_; ++s) {
        // ===== fused barrier-3 + flag broadcast: poll 32 self-tagged words =====
        if (tid < 32) {
            unsigned long long w = ld_u64(&wq[tid]);
            while (!((unsigned)(w >> 32) >= (unsigned)s || !(w & 2ULL))) {
                __builtin_amdgcn_s_sleep(1);
                w = ld_u64(&wq[tid]);
            }
            s_w[tid]    = w;
            s_ti[tid]   = (int)((w >> 2) & 511ULL);
            s_last[tid] = (int)((w >> 11) & 31ULL) - 1;
            s_sa[tid]   = (int)((w >> 16) & 7ULL);
            s_lc[tid]   = (int)((w >> 19) & 511ULL);
        }
        __syncthreads();
        if (tid == 0) {
            unsigned nbm = 0, actm = 0;
            for (int q = 0; q < 32; ++q) {
                unsigned long long w = s_w[q];
                nbm  |= (unsigned)(w & 1ULL) << q;
                actm |= (unsigned)((w >> 1) & 1ULL) << q;
            }
            s_nbm = nbm; s_actm = actm;
        }
        __syncthreads();
        const unsigned nbm = s_nbm, actm = s_actm;
        if (!actm) break;
        const int par = s & 1;

        if (nbm) {
            // ================= S1: LSTM0 (+ prefetch S2 operands) =================
            if (tid < 128) {
                int bb = tid & 31, jj = tid >> 5;
                int sb = (sel_mask >> bb) & 1;
                if ((nbm >> bb) & 1) {
                    cs0[tid] = ld_f(&Xb[XI(sb,1,j0+jj,bb)]);   // c0 cur
                    cs1[tid] = ld_f(&Xb[XI(sb,3,j0+jj,bb)]);   // c1 cur (for S2)
                }
            }
            for (int i = tid; i < B_*PRED_; i += BDEC) {
                int bb = i & 31, kk = i >> 5;
                int sb = (sel_mask >> bb) & 1;
                if ((nbm >> bb) & 1) {
                    hs0[bb*321 + kk] = ld_f(&Xb[XI(sb,0,kk,bb)]);  // h0 cur
                    hs1[bb*321 + kk] = ld_f(&Xb[XI(sb,2,kk,bb)]);  // h1 cur (for S2)
                }
            }
            __syncthreads();
            if ((nbm >> b) & 1) {
                const float* hrow = &hs0[b*321];
                int k0 = ks * 80;
                float a0=0.f, a1=0.f, a2=0.f, a3=0.f;
                #pragma unroll 4
                for (int kk = k0; kk < k0 + 80; kk += 4) {
                    float h0v = hrow[kk+0], h1v = hrow[kk+1];
                    float h2v = hrow[kk+2], h3v = hrow[kk+3];
                    float4 w0 = *(const float4*)&wh0_s[0*4+jl][kk];
                    float4 w1 = *(const float4*)&wh0_s[1*4+jl][kk];
                    float4 w2 = *(const float4*)&wh0_s[2*4+jl][kk];
                    float4 w3 = *(const float4*)&wh0_s[3*4+jl][kk];
                    a0 += w0.x*h0v + w0.y*h1v + w0.z*h2v + w0.w*h3v;
                    a1 += w1.x*h0v + w1.y*h1v + w1.z*h2v + w1.w*h3v;
                    a2 += w2.x*h0v + w2.y*h1v + w2.z*h2v + w2.w*h3v;
                    a3 += w3.x*h0v + w3.y*h1v + w3.z*h2v + w3.w*h3v;
                }
                parts[((0*4+ks)*4+jl)*32+b] = a0;
                parts[((1*4+ks)*4+jl)*32+b] = a1;
                parts[((2*4+ks)*4+jl)*32+b] = a2;
                parts[((3*4+ks)*4+jl)*32+b] = a3;
            }
            __syncthreads();
            if (tid < 128) {
                int bb = tid & 31, jj = tid >> 5;
                if ((nbm >> bb) & 1) {
                    int j = j0 + jj;
                    int sb = (sel_mask >> bb) & 1;
                    int ls = s_last[bb];
                    float gt[4];
                    #pragma unroll
                    for (int g4 = 0; g4 < 4; ++g4) {
                        float v = parts[((g4*4+0)*4+jj)*32+bb] + parts[((g4*4+1)*4+jj)*32+bb]
                                + parts[((g4*4+2)*4+jj)*32+bb] + parts[((g4*4+3)*4+jj)*32+bb];
                        v += b0_s[g4*4+jj];
                        if (ls >= 0) v += we_s[ls][g4*4+jj];
                        gt[g4] = v;
                    }
                    float cold = cs0[tid];
                    float cn = sigm(gt[1])*cold + sigm(gt[0])*tanhf(gt[2]);
                    float hn = sigm(gt[3])*tanhf(cn);
                    st_f(&Xb[XI(sb^1,0,j,bb)], hn);
                    st_f(&Xb[XI(sb^1,1,j,bb)], cn);
                }
            }
            __syncthreads();  // drains vmcnt: candidate stores globally visible
            // ---- bar1: self-tagged arrival, direct poll (1 RT) ----
            if (tid == 0) st_i(&arr1[blk], s + 1);
            if (tid < GDEC) { while (ld_i(&arr1[tid]) < s + 1) __builtin_amdgcn_s_sleep(1); }
            __syncthreads();

            // ================= S2: LSTM1 =================
            for (int i = tid; i < B_*PRED_; i += BDEC) {
                int bb = i & 31, kk = i >> 5;
                int sb = (sel_mask >> bb) & 1;
                if ((nbm >> bb) & 1)
                    hs0[bb*321 + kk] = ld_f(&Xb[XI(sb^1,0,kk,bb)]);  // h0 candidate
            }
            __syncthreads();
            if ((nbm >> b) & 1) {
                const float* hxr = &hs0[b*321];
                const float* hhr = &hs1[b*321];
                const float* wh1r0 = Wh1 + ((size_t)(0*PRED_ + j0 + jl))*PRED_;
                const float* wh1r1 = Wh1 + ((size_t)(1*PRED_ + j0 + jl))*PRED_;
                const float* wh1r2 = Wh1 + ((size_t)(2*PRED_ + j0 + jl))*PRED_;
                const float* wh1r3 = Wh1 + ((size_t)(3*PRED_ + j0 + jl))*PRED_;
                int k0 = ks * 80;
                float a0=0.f, a1=0.f, a2=0.f, a3=0.f;
                #pragma unroll 2
                for (int kk = k0; kk < k0 + 80; kk += 4) {
                    float x0 = hxr[kk+0], x1 = hxr[kk+1], x2 = hxr[kk+2], x3 = hxr[kk+3];
                    float y0 = hhr[kk+0], y1 = hhr[kk+1], y2 = hhr[kk+2], y3 = hhr[kk+3];
                    float4 wa0 = *(const float4*)&wi1_s[0*4+jl][kk];
                    float4 wa1 = *(const float4*)&wi1_s[1*4+jl][kk];
                    float4 wa2 = *(const float4*)&wi1_s[2*4+jl][kk];
                    float4 wa3 = *(const float4*)&wi1_s[3*4+jl][kk];
                    float4 wb0 = *(const float4*)(wh1r0 + kk);
                    float4 wb1 = *(const float4*)(wh1r1 + kk);
                    float4 wb2 = *(const float4*)(wh1r2 + kk);
                    float4 wb3 = *(const float4*)(wh1r3 + kk);
                    a0 += wa0.x*x0+wa0.y*x1+wa0.z*x2+wa0.w*x3 + wb0.x*y0+wb0.y*y1+wb0.z*y2+wb0.w*y3;
                    a1 += wa1.x*x0+wa1.y*x1+wa1.z*x2+wa1.w*x3 + wb1.x*y0+wb1.y*y1+wb1.z*y2+wb1.w*y3;
                    a2 += wa2.x*x0+wa2.y*x1+wa2.z*x2+wa2.w*x3 + wb2.x*y0+wb2.y*y1+wb2.z*y2+wb2.w*y3;
                    a3 += wa3.x*x0+wa3.y*x1+wa3.z*x2+wa3.w*x3 + wb3.x*y0+wb3.y*y1+wb3.z*y2+wb3.w*y3;
                }
                parts[((0*4+ks)*4+jl)*32+b] = a0;
                parts[((1*4+ks)*4+jl)*32+b] = a1;
                parts[((2*4+ks)*4+jl)*32+b] = a2;
                parts[((3*4+ks)*4+jl)*32+b] = a3;
            }
            __syncthreads();
            if (tid < 128) {
                int bb = tid & 31, jj = tid >> 5;
                if ((nbm >> bb) & 1) {
                    int j = j0 + jj;
                    int sb = (sel_mask >> bb) & 1;
                    float gt[4];
                    #pragma unroll
                    for (int g4 = 0; g4 < 4; ++g4) {
                        float v = parts[((g4*4+0)*4+jj)*32+bb] + parts[((g4*4+1)*4+jj)*32+bb]
                                + parts[((g4*4+2)*4+jj)*32+bb] + parts[((g4*4+3)*4+jj)*32+bb];
                        v += b1_s[g4*4+jj];
                        gt[g4] = v;
                    }
                    float cold = cs1[tid];
                    float cn = sigm(gt[1])*cold + sigm(gt[0])*tanhf(gt[2]);
                    float hn = sigm(gt[3])*tanhf(cn);
                    st_f(&Xb[XI(sb^1,2,j,bb)], hn);
                    st_f(&Xb[XI(sb^1,3,j,bb)], cn);
                }
            }
            __syncthreads();
            // ---- bar2 ----
            if (tid == 0) st_i(&arr2[blk], s + 1);
            if (tid < GDEC) { while (ld_i(&arr2[tid]) < s + 1) __builtin_amdgcn_s_sleep(1); }
            __syncthreads();
        }

        // ===== S3: joint (v-split over 64 blocks) + logits + per-b finalize =====
        if (blk < 64) {
            const unsigned needm = actm & nbm;
            for (int i = tid; i < B_*PRED_; i += BDEC) {
                int bb = i & 31, kk = i >> 5;
                if ((needm >> bb) & 1)
                    hs0[bb*321 + kk] = ld_f(&Xb[XI(((sel_mask>>bb)&1)^1,2,kk,bb)]);  // h1 cand
            }
            __syncthreads();
            {
                const int b3 = tid & 31, v3 = (tid >> 5) & 7, ks3 = tid >> 8;  // ks3: 0/1
                float p = 0.f;
                if ((needm >> b3) & 1) {
                    const float* hrow = &hs0[b3*321];
                    int k0 = ks3 * 160;
                    #pragma unroll 4
                    for (int kk = k0; kk < k0 + 160; kk += 4) {
                        float4 w4 = *(const float4*)&wt_s[v3][kk];
                        p += w4.x*hrow[kk+0] + w4.y*hrow[kk+1]
                           + w4.z*hrow[kk+2] + w4.w*hrow[kk+3];
                    }
                }
                parts[ks3*256 + v3*32 + b3] = p;
            }
            __syncthreads();
            if (tid < 256) {
                int bb = tid & 31, vv = tid >> 5;
                if ((actm >> bb) & 1) {
                    float jg;
                    int gidx = bb*JH_ + blk*8 + vv;
                    if ((nbm >> bb) & 1) {
                        jg = parts[vv*32+bb] + parts[256 + vv*32+bb];
                        JGg[gidx] = jg;            // block-private: normal store
                    } else {
                        jg = JGg[gidx];
                    }
                    int tm = min(s_ti[bb], T_ - 1);
                    float hv = FP[((size_t)bb*T_ + tm)*JH_ + blk*8 + vv] + jg;
                    hid[bb*8 + vv] = fmaxf(hv, 0.f);
                }
            }
            __syncthreads();
            {
                int bb = tid >> 4, lh = tid & 15;
                if ((actm >> bb) & 1) {
                    const float* hb = &hid[bb*8];
                    float h0=hb[0],h1=hb[1],h2=hb[2],h3=hb[3];
                    float h4=hb[4],h5=hb[5],h6=hb[6],h7=hb[7];
                    const float* w = wj2_s[lh];
                    float acc = w[0]*h0+w[1]*h1+w[2]*h2+w[3]*h3+w[4]*h4+w[5]*h5+w[6]*h6+w[7]*h7;
                    atomicAdd(&LG[par*1024 + bb*32 + lh], acc);
                    if (lh < VOCAB_ - 16) {
                        const float* w2 = wj2_s[lh+16];
                        float acc2 = w2[0]*h0+w2[1]*h1+w2[2]*h2+w2[3]*h3+w2[4]*h4+w2[5]*h5+w2[6]*h6+w2[7]*h7;
                        atomicAdd(&LG[par*1024 + bb*32 + lh + 16], acc2);
                    }
                }
            }
            __syncthreads();   // drain atomics (vmcnt(0) per wave before barrier)
            if (tid < 32 && ((actm >> tid) & 1)) {
                const int bb = tid;
                int c = ++s_cnt[bb];                       // active-step count (identical in all 64 blocks)
                int old = atomicAdd(&done[bb], 1);         // monotonic, no reset
                if (old == 64*c - 1) {
                    // last contributor: all 64 blocks' LG adds for step s are visible
                    float best = -1e30f; int bi = 0;
                    for (int l = 0; l < VOCAB_; ++l) {
                        float v = ld_f(&LG[par*1024 + bb*32 + l]) + bj2[l];
                        if (v > best) { best = v; bi = l; }
                    }
                    const int blankness = (bi == BLANK_) ? 1 : 0;
                    int tiv = s_ti[bb] + blankness;
                    unsigned long long nw;
                    if (tiv >= out_lens[bb]) {
                        nw = ((unsigned long long)(s+1) << 32)
                           | ((unsigned long long)(tiv & 511) << 2);   // nb=0, act=0
                    } else {
                        int notb = 1 - blankness;
                        int sav = blankness ? 0 : s_sa[bb];
                        int nl = s_last[bb];
                        int lcn = s_lc[bb];
                        if (notb) {
                            lcn += 1;
                            if (lcn < NSTEPS_) st_i(&out[bb*NSTEPS_ + lcn], bi);
                            st_i(&out[B_*NSTEPS_ + bb], lcn);
                            nl = bi;
                            sav += 1;
                        }
                        if (sav >= MAXSYM_) { tiv += 1; sav = 0; }
                        nw = ((unsigned long long)(s+1) << 32)
                           | ((unsigned long long)(lcn & 511) << 19)
                           | ((unsigned long long)(sav & 7) << 16)
                           | ((unsigned long long)((nl+1) & 31) << 11)
                           | ((unsigned long long)(tiv & 511) << 2)
                           | 2ULL | (unsigned long long)notb;
                    }
                    // reset parity buffer for reuse at step s+2 (visibility via this
                    // block's subsequent __syncthreads vmcnt drain, causally before
                    // any s+2 contributor passes its barriers)
                    for (int l = 0; l < VOCAB_; ++l) st_f(&LG[par*1024 + bb*32 + l], 0.f);
                    st_u64(&wq[bb], nw);
                }
            }
        }
        sel_mask ^= nbm;
    }
}

extern "C" void kernel_launch(void* const* d_in, const int* in_sizes, int n_in,
                              void* d_out, int out_size, void* d_ws, size_t ws_size,
                              hipStream_t stream) {
    const float* x    = (const float*)d_in[0];
    const int*   olen = (const int*)d_in[1];
    const float* emb  = (const float*)d_in[2];
    const float* Wi0  = (const float*)d_in[3];
    const float* Wh0  = (const float*)d_in[4];
    const float* b0   = (const float*)d_in[5];
    const float* Wi1  = (const float*)d_in[6];
    const float* Wh1  = (const float*)d_in[7];
    const float* b1   = (const float*)d_in[8];
    const float* Wj1  = (const float*)d_in[9];
    const float* bj1  = (const float*)d_in[10];
    const float* Wj2  = (const float*)d_in[11];
    const float* bj2  = (const float*)d_in[12];
    float* ws = (float*)d_ws;
    int* out = (int*)d_out;

    hipLaunchKernelGGL(k_init, dim3(256), dim3(256), 0, stream, ws, out);
    hipLaunchKernelGGL(k_we,   dim3(28*5), dim3(256), 0, stream, emb, Wi0, ws);
    hipLaunchKernelGGL(k_fpre, dim3(T_*8), dim3(256), 0, stream, x, Wj1, bj1, ws);
    hipLaunchKernelGGL(k_decode, dim3(GDEC), dim3(BDEC), 0, stream,
                       olen, Wh0, b0, Wi1, Wh1, b1, Wj1, Wj2, bj2, ws, out);
}

// Round 5
// 8719.575 us; speedup vs baseline: 2.5559x; 1.1876x over previous
//
#include <hip/hip_runtime.h>
#include <math.h>

#define B_ 32
#define T_ 48
#define ENC_ 1024
#define PRED_ 320
#define G4P (4*PRED_)        // 1280
#define JH_ 512
#define NJ_ (ENC_+PRED_)     // 1344
#define VOCAB_ 29
#define BLANK_ 28
#define MAXSYM_ 6
#define NSTEPS_ (T_*MAXSYM_) // 288
#define GDEC 80
#define BDEC 512

// ---- workspace layout ----
#define FPRE_OFF 0                       // 786432 floats
#define WE_OFF   786432                  // 35840
#define H0C_OFF  822272                  // 10240  h0 candidates [k][b]
#define H1C_OFF  832512                  // 10240  h1 candidates [k][b]
#define HID_OFF  842752                  // 64*256 hid slices [vblk][vv][b]
#define INT_OFF  859136                  // int-index base into (int*)ws
#define W_I   (INT_OFF + 0)              // 32 u64 packed per-b words (64 ints)
#define TA_I  (INT_OFF + 64)             // 80 tags, stride 16 ints (own line)
#define TB_I  (INT_OFF + 1344)           // 80 tags
#define TS_I  (INT_OFF + 2624)           // 80 consume-ack tags
#define TC_I  (INT_OFF + 3904)           // 64 hid tags
// w word: [0] nb, [1] act, [10:2] ti, [15:11] last+1, [18:16] sa, [27:19] lc, [63:32] tag

__device__ __forceinline__ float sigm(float v) { return 1.0f / (1.0f + expf(-v)); }

__device__ __forceinline__ int  ld_i(const int* p)   { return __hip_atomic_load((int*)p, __ATOMIC_RELAXED, __HIP_MEMORY_SCOPE_AGENT); }
__device__ __forceinline__ void st_i(int* p, int v)  { __hip_atomic_store(p, v, __ATOMIC_RELAXED, __HIP_MEMORY_SCOPE_AGENT); }
__device__ __forceinline__ float ld_f(const float* p){ return __hip_atomic_load((float*)p, __ATOMIC_RELAXED, __HIP_MEMORY_SCOPE_AGENT); }
__device__ __forceinline__ void st_f(float* p, float v){ __hip_atomic_store(p, v, __ATOMIC_RELAXED, __HIP_MEMORY_SCOPE_AGENT); }
__device__ __forceinline__ unsigned long long ld_u64(const unsigned long long* p){
    return __hip_atomic_load((unsigned long long*)p, __ATOMIC_RELAXED, __HIP_MEMORY_SCOPE_AGENT); }
__device__ __forceinline__ void st_u64(unsigned long long* p, unsigned long long v){
    __hip_atomic_store(p, v, __ATOMIC_RELAXED, __HIP_MEMORY_SCOPE_AGENT); }

// ---------------- init ----------------
__global__ void k_init(float* __restrict__ ws, int* __restrict__ out) {
    int idx = blockIdx.x * blockDim.x + threadIdx.x;
    int stride = gridDim.x * blockDim.x;
    int* wi = (int*)ws;
    for (int i = idx; i < 2*B_*PRED_; i += stride) { ws[H0C_OFF + i] = 0.f; }
    for (int i = idx; i < 64*256; i += stride) ws[HID_OFF + i] = 0.f;
    for (int i = idx; i < 4864; i += stride) wi[TA_I + i] = 0;   // TA..TC all tags
    for (int i = idx; i < B_*NSTEPS_; i += stride) out[i] = -1;  // lt
    if (idx < 32) {
        ((unsigned long long*)(wi + W_I))[idx] = 3ULL;  // nb=1 act=1 ti=0 last=-1 sa=0 lc=0 tag=0
        out[B_*NSTEPS_ + idx] = 0;                      // lc
    }
}

// ---------------- WE = emb @ Wi0^T  (28 x 1280) ----------------
__global__ __launch_bounds__(256) void k_we(const float* __restrict__ emb,
                                            const float* __restrict__ Wi0,
                                            float* __restrict__ ws) {
    __shared__ float es[PRED_];
    int l = blockIdx.x / 5;
    int rq = blockIdx.x % 5;
    int t = threadIdx.x;
    if (t < PRED_) es[t] = emb[l*PRED_ + t];
    if (t + 256 < PRED_) es[t + 256] = emb[l*PRED_ + t + 256];
    __syncthreads();
    int r = rq*256 + t;
    const float4* wr = (const float4*)(Wi0 + (size_t)r*PRED_);
    float acc = 0.0f;
    #pragma unroll 4
    for (int k4 = 0; k4 < PRED_/4; ++k4) {
        float4 w = wr[k4];
        acc += w.x*es[4*k4] + w.y*es[4*k4+1] + w.z*es[4*k4+2] + w.w*es[4*k4+3];
    }
    ws[WE_OFF + l*G4P + r] = acc;
}

// ---------------- Fpre[b][t][j] = x[b,t]·Wj1[j,:1024] + bj1[j] ----------------
__global__ __launch_bounds__(256) void k_fpre(const float* __restrict__ x,
                                              const float* __restrict__ Wj1,
                                              const float* __restrict__ bj1,
                                              float* __restrict__ ws) {
    __shared__ float As[B_][129];
    __shared__ float Bs[64][129];
    int tt = blockIdx.x >> 3;
    int jb = blockIdx.x & 7;
    int tid = threadIdx.x;
    int b = tid >> 3, jq = tid & 7;
    float acc[8] = {0,0,0,0,0,0,0,0};
    for (int kc = 0; kc < ENC_; kc += 128) {
        for (int i = tid; i < B_*128; i += 256) {
            int bb = i >> 7, kk = i & 127;
            As[bb][kk] = x[((size_t)bb*T_ + tt)*ENC_ + kc + kk];
        }
        for (int i = tid; i < 64*128; i += 256) {
            int jj = i >> 7, kk = i & 127;
            Bs[jj][kk] = Wj1[((size_t)(jb*64 + jj))*NJ_ + kc + kk];
        }
        __syncthreads();
        for (int kk = 0; kk < 128; ++kk) {
            float a = As[b][kk];
            #pragma unroll
            for (int u = 0; u < 8; ++u) acc[u] += a * Bs[jq*8 + u][kk];
        }
        __syncthreads();
    }
    #pragma unroll
    for (int u = 0; u < 8; ++u) {
        int j = jb*64 + jq*8 + u;
        ws[FPRE_OFF + ((size_t)b*T_ + tt)*JH_ + j] = acc[u] + bj1[j];
    }
}

// ---------------- persistent decode ----------------
__global__ __launch_bounds__(BDEC) void k_decode(
    const int* __restrict__ out_lens,
    const float* __restrict__ Wh0, const float* __restrict__ b0,
    const float* __restrict__ Wi1, const float* __restrict__ Wh1,
    const float* __restrict__ b1,
    const float* __restrict__ Wj1,
    const float* __restrict__ Wj2, const float* __restrict__ bj2,
    float* __restrict__ ws, int* __restrict__ out)
{
    float* H0C = ws + H0C_OFF;
    float* H1C = ws + H1C_OFF;
    float* HID = ws + HID_OFF;
    const float* WE = ws + WE_OFF;
    const float* FP = ws + FPRE_OFF;
    int* wi = (int*)ws;
    int* tagA = wi + TA_I;
    int* tagB = wi + TB_I;
    int* tagS = wi + TS_I;
    int* tagC = wi + TC_I;
    unsigned long long* wq = (unsigned long long*)(wi + W_I);

    __shared__ __align__(16) float wh0_s[16][PRED_];   // 20 KB
    __shared__ __align__(16) float wi1_s[16][PRED_];   // 20 KB
    __shared__ __align__(16) float wt_s[8][PRED_];     // 10 KB (blocks<64)
    __shared__ float hs0[B_*321];                      // 41 KB  h0 state/cand
    __shared__ float hs1[B_*321];                      // 41 KB  h1 state/cand
    __shared__ float c0cur[128], c0cand[128], c1cur[128], c1cand[128];
    __shared__ float jg_c[256];                        // cached jg slice
    __shared__ float we_s[28][16];
    __shared__ float b0_s[16], b1_s[16];
    __shared__ float parts[2048];                      // partials / logit scratch
    __shared__ float hid_s[JH_];
    __shared__ unsigned long long s_w[32];
    __shared__ int s_ti[32], s_last[32], s_sa[32], s_lc[32];
    __shared__ unsigned s_nbm, s_actm;

    const int tid = threadIdx.x;
    const int blk = blockIdx.x;
    const int j0  = blk * 4;

    // ---- one-time preload ----
    for (int i = tid; i < 16*PRED_; i += BDEC) {
        int r = i / PRED_, c = i % PRED_;
        int g = r >> 2, jl = r & 3;
        wh0_s[r][c] = Wh0[((size_t)(g*PRED_ + j0 + jl))*PRED_ + c];
        wi1_s[r][c] = Wi1[((size_t)(g*PRED_ + j0 + jl))*PRED_ + c];
    }
    if (blk < 64) {
        for (int i = tid; i < 8*PRED_; i += BDEC) {
            int v = i / PRED_, k = i % PRED_;
            wt_s[v][k] = Wj1[((size_t)(blk*8 + v))*NJ_ + ENC_ + k];
        }
    }
    for (int i = tid; i < 28*16; i += BDEC) {
        int ls = i >> 4, r = i & 15;
        int g = r >> 2, jl = r & 3;
        we_s[ls][r] = WE[(size_t)ls*G4P + g*PRED_ + j0 + jl];
    }
    if (tid < 16) {
        int g = tid >> 2, jl = tid & 3;
        b0_s[tid] = b0[g*PRED_ + j0 + jl];
        b1_s[tid] = b1[g*PRED_ + j0 + jl];
    }
    for (int i = tid; i < B_*321; i += BDEC) { hs0[i] = 0.f; hs1[i] = 0.f; }
    if (tid < 128) { c0cur[tid]=0.f; c0cand[tid]=0.f; c1cur[tid]=0.f; c1cand[tid]=0.f; }
    for (int i = tid; i < 256; i += BDEC) jg_c[i] = 0.f;
    __syncthreads();

    const int b  = tid & 31;
    const int jl = (tid >> 5) & 3;
    const int ks = tid >> 7;       // 0..3

    for (int s = 0; s < NSTEPS_; ++s) {
        // ===== hop D: poll per-b decision words (barrier + flags + exit) =====
        if (tid < 32) {
            unsigned long long w = ld_u64(&wq[tid]);
            while (!((unsigned)(w >> 32) >= (unsigned)s || !(w & 2ULL))) {
                __builtin_amdgcn_s_sleep(2);
                w = ld_u64(&wq[tid]);
            }
            s_w[tid]    = w;
            s_ti[tid]   = (int)((w >> 2) & 511ULL);
            s_last[tid] = (int)((w >> 11) & 31ULL) - 1;
            s_sa[tid]   = (int)((w >> 16) & 7ULL);
            s_lc[tid]   = (int)((w >> 19) & 511ULL);
        }
        __syncthreads();
        if (tid == 0) {
            unsigned nbm = 0, actm = 0;
            for (int q = 0; q < 32; ++q) {
                unsigned long long w = s_w[q];
                nbm  |= (unsigned)(w & 1ULL) << q;
                actm |= (unsigned)((w >> 1) & 1ULL) << q;
            }
            s_nbm = nbm; s_actm = actm;
        }
        __syncthreads();
        const unsigned nbm = s_nbm, actm = s_actm;
        if (!actm) break;
        // commit accepted c-candidates (same-thread mapping tid = jj*32+bb)
        if (tid < 128) {
            int bb = tid & 31;
            if ((nbm >> bb) & 1) { c0cur[tid] = c0cand[tid]; c1cur[tid] = c1cand[tid]; }
        }
        __syncthreads();

        if (nbm) {
            // ================= S1: LSTM0 (operands fully LDS-resident) =========
            if ((nbm >> b) & 1) {
                const float* hrow = &hs0[b*321];
                int k0 = ks * 80;
                float a0=0.f, a1=0.f, a2=0.f, a3=0.f;
                #pragma unroll 4
                for (int kk = k0; kk < k0 + 80; kk += 4) {
                    float h0v = hrow[kk+0], h1v = hrow[kk+1];
                    float h2v = hrow[kk+2], h3v = hrow[kk+3];
                    float4 w0 = *(const float4*)&wh0_s[0*4+jl][kk];
                    float4 w1 = *(const float4*)&wh0_s[1*4+jl][kk];
                    float4 w2 = *(const float4*)&wh0_s[2*4+jl][kk];
                    float4 w3 = *(const float4*)&wh0_s[3*4+jl][kk];
                    a0 += w0.x*h0v + w0.y*h1v + w0.z*h2v + w0.w*h3v;
                    a1 += w1.x*h0v + w1.y*h1v + w1.z*h2v + w1.w*h3v;
                    a2 += w2.x*h0v + w2.y*h1v + w2.z*h2v + w2.w*h3v;
                    a3 += w3.x*h0v + w3.y*h1v + w3.z*h2v + w3.w*h3v;
                }
                parts[((0*4+ks)*4+jl)*32+b] = a0;
                parts[((1*4+ks)*4+jl)*32+b] = a1;
                parts[((2*4+ks)*4+jl)*32+b] = a2;
                parts[((3*4+ks)*4+jl)*32+b] = a3;
            }
            __syncthreads();
            if (tid < 128) {
                int bb = tid & 31, jj = tid >> 5;
                if ((nbm >> bb) & 1) {
                    int ls = s_last[bb];
                    float gt[4];
                    #pragma unroll
                    for (int g4 = 0; g4 < 4; ++g4) {
                        float v = parts[((g4*4+0)*4+jj)*32+bb] + parts[((g4*4+1)*4+jj)*32+bb]
                                + parts[((g4*4+2)*4+jj)*32+bb] + parts[((g4*4+3)*4+jj)*32+bb];
                        v += b0_s[g4*4+jj];
                        if (ls >= 0) v += we_s[ls][g4*4+jj];
                        gt[g4] = v;
                    }
                    float cold = c0cur[tid];
                    float cn = sigm(gt[1])*cold + sigm(gt[0])*tanhf(gt[2]);
                    float hn = sigm(gt[3])*tanhf(cn);
                    c0cand[tid] = cn;
                    st_f(&H0C[(j0+jj)*32 + bb], hn);      // publish candidate
                }
            }
            __syncthreads();   // drain candidate stores (release)
            if (tid == 0) st_i(&tagA[blk*16], s + 1);
            // ---- hop A detect + stage ----
            if (tid < GDEC) { while (ld_i(&tagA[tid*16]) < s + 1) __builtin_amdgcn_s_sleep(2); }
            __syncthreads();
            for (int i = tid; i < B_*PRED_; i += BDEC) {
                int bb = i & 31, kk = i >> 5;
                if ((nbm >> bb) & 1) hs0[bb*321 + kk] = ld_f(&H0C[kk*32 + bb]);
            }
            __syncthreads();

            // ================= S2: LSTM1 =================
            if ((nbm >> b) & 1) {
                const float* hxr = &hs0[b*321];   // h0 candidate
                const float* hhr = &hs1[b*321];   // h1 current
                const float* wh1r0 = Wh1 + ((size_t)(0*PRED_ + j0 + jl))*PRED_;
                const float* wh1r1 = Wh1 + ((size_t)(1*PRED_ + j0 + jl))*PRED_;
                const float* wh1r2 = Wh1 + ((size_t)(2*PRED_ + j0 + jl))*PRED_;
                const float* wh1r3 = Wh1 + ((size_t)(3*PRED_ + j0 + jl))*PRED_;
                int k0 = ks * 80;
                float a0=0.f, a1=0.f, a2=0.f, a3=0.f;
                #pragma unroll 2
                for (int kk = k0; kk < k0 + 80; kk += 4) {
                    float x0 = hxr[kk+0], x1 = hxr[kk+1], x2 = hxr[kk+2], x3 = hxr[kk+3];
                    float y0 = hhr[kk+0], y1 = hhr[kk+1], y2 = hhr[kk+2], y3 = hhr[kk+3];
                    float4 wa0 = *(const float4*)&wi1_s[0*4+jl][kk];
                    float4 wa1 = *(const float4*)&wi1_s[1*4+jl][kk];
                    float4 wa2 = *(const float4*)&wi1_s[2*4+jl][kk];
                    float4 wa3 = *(const float4*)&wi1_s[3*4+jl][kk];
                    float4 wb0 = *(const float4*)(wh1r0 + kk);
                    float4 wb1 = *(const float4*)(wh1r1 + kk);
                    float4 wb2 = *(const float4*)(wh1r2 + kk);
                    float4 wb3 = *(const float4*)(wh1r3 + kk);
                    a0 += wa0.x*x0+wa0.y*x1+wa0.z*x2+wa0.w*x3 + wb0.x*y0+wb0.y*y1+wb0.z*y2+wb0.w*y3;
                    a1 += wa1.x*x0+wa1.y*x1+wa1.z*x2+wa1.w*x3 + wb1.x*y0+wb1.y*y1+wb1.z*y2+wb1.w*y3;
                    a2 += wa2.x*x0+wa2.y*x1+wa2.z*x2+wa2.w*x3 + wb2.x*y0+wb2.y*y1+wb2.z*y2+wb2.w*y3;
                    a3 += wa3.x*x0+wa3.y*x1+wa3.z*x2+wa3.w*x3 + wb3.x*y0+wb3.y*y1+wb3.z*y2+wb3.w*y3;
                }
                parts[((0*4+ks)*4+jl)*32+b] = a0;
                parts[((1*4+ks)*4+jl)*32+b] = a1;
                parts[((2*4+ks)*4+jl)*32+b] = a2;
                parts[((3*4+ks)*4+jl)*32+b] = a3;
            }
            __syncthreads();
            if (tid < 128) {
                int bb = tid & 31, jj = tid >> 5;
                if ((nbm >> bb) & 1) {
                    float gt[4];
                    #pragma unroll
                    for (int g4 = 0; g4 < 4; ++g4) {
                        float v = parts[((g4*4+0)*4+jj)*32+bb] + parts[((g4*4+1)*4+jj)*32+bb]
                                + parts[((g4*4+2)*4+jj)*32+bb] + parts[((g4*4+3)*4+jj)*32+bb];
                        v += b1_s[g4*4+jj];
                        gt[g4] = v;
                    }
                    float cold = c1cur[tid];
                    float cn = sigm(gt[1])*cold + sigm(gt[0])*tanhf(gt[2]);
                    float hn = sigm(gt[3])*tanhf(cn);
                    c1cand[tid] = cn;
                    st_f(&H1C[(j0+jj)*32 + bb], hn);
                }
            }
            __syncthreads();
            if (tid == 0) st_i(&tagB[blk*16], s + 1);
            // ---- hop B detect + stage ----
            if (tid < GDEC) { while (ld_i(&tagB[tid*16]) < s + 1) __builtin_amdgcn_s_sleep(2); }
            __syncthreads();
            for (int i = tid; i < B_*PRED_; i += BDEC) {
                int bb = i & 31, kk = i >> 5;
                if ((nbm >> bb) & 1) hs1[bb*321 + kk] = ld_f(&H1C[kk*32 + bb]);
            }
            __syncthreads();
            if (tid == 0) st_i(&tagS[blk*16], s + 1);   // consume-ack
        } else {
            if (tid == 0) st_i(&tagS[blk*16], s + 1);   // blank step: ack immediately
        }

        // ===== S3a: v-split joint → hid publish (blocks 0..63) =====
        if (blk < 64) {
            if (nbm) {
                const unsigned needm = nbm & actm;
                const int b3 = tid & 31, v3 = (tid >> 5) & 7, ks3 = tid >> 8;  // 0/1
                float p = 0.f;
                if ((needm >> b3) & 1) {
                    const float* hrow = &hs1[b3*321];
                    int k0 = ks3 * 160;
                    #pragma unroll 4
                    for (int kk = k0; kk < k0 + 160; kk += 4) {
                        float4 w4 = *(const float4*)&wt_s[v3][kk];
                        p += w4.x*hrow[kk+0] + w4.y*hrow[kk+1]
                           + w4.z*hrow[kk+2] + w4.w*hrow[kk+3];
                    }
                }
                parts[ks3*256 + v3*32 + b3] = p;
                __syncthreads();
                if (tid < 256) {
                    int bb = tid & 31, vv = tid >> 5;
                    if ((needm >> bb) & 1)
                        jg_c[vv*32 + bb] = parts[vv*32+bb] + parts[256 + vv*32+bb];
                }
                __syncthreads();
            }
            if (tid < 256) {
                int bb = tid & 31, vv = tid >> 5;
                if ((actm >> bb) & 1) {
                    int tm = min(s_ti[bb], T_ - 1);
                    float hv = FP[((size_t)bb*T_ + tm)*JH_ + blk*8 + vv] + jg_c[vv*32 + bb];
                    st_f(&HID[blk*256 + vv*32 + bb], fmaxf(hv, 0.f));
                }
            }
            __syncthreads();
            if (tid == 0) st_i(&tagC[blk*16], s + 1);
        }

        // ===== S3b: per-b finalize (blocks 0..31) =====
        if (blk < 32 && ((actm >> blk) & 1)) {
            if (tid < 144) {
                const int* tp = (tid < 80) ? &tagS[tid*16] : &tagC[(tid-80)*16];
                while (ld_i(tp) < s + 1) __builtin_amdgcn_s_sleep(2);
            }
            __syncthreads();
            hid_s[tid] = ld_f(&HID[(tid >> 3)*256 + (tid & 7)*32 + blk]);
            __syncthreads();
            {
                int l = tid & 31, c = tid >> 5;   // c: 0..15
                float acc = 0.f;
                if (l < VOCAB_) {
                    const float4* wr = (const float4*)(Wj2 + (size_t)l*JH_ + c*32);
                    const float* hr = &hid_s[c*32];
                    #pragma unroll
                    for (int u = 0; u < 8; ++u) {
                        float4 w = wr[u];
                        acc += w.x*hr[4*u] + w.y*hr[4*u+1] + w.z*hr[4*u+2] + w.w*hr[4*u+3];
                    }
                }
                parts[c*32 + l] = acc;
            }
            __syncthreads();
            if (tid < 32) {
                float v = 0.f;
                #pragma unroll
                for (int p = 0; p < 16; ++p) v += parts[p*32 + tid];
                parts[512 + tid] = (tid < VOCAB_) ? (v + bj2[tid]) : -1e30f;
            }
            __syncthreads();
            if (tid == 0) {
                const int bb = blk;
                float best = parts[512]; int bi = 0;
                for (int l2 = 1; l2 < VOCAB_; ++l2) {
                    float vv = parts[512 + l2];
                    if (vv > best) { best = vv; bi = l2; }
                }
                const int blankness = (bi == BLANK_) ? 1 : 0;
                int tiv = s_ti[bb] + blankness;
                unsigned long long nw;
                if (tiv >= out_lens[bb]) {
                    nw = ((unsigned long long)(s+1) << 32)
                       | ((unsigned long long)(tiv & 511) << 2);   // nb=0 act=0
                } else {
                    int notb = 1 - blankness;
                    int sav = blankness ? 0 : s_sa[bb];
                    int nl = s_last[bb];
                    int lcn = s_lc[bb];
                    if (notb) {
                        lcn += 1;
                        if (lcn < NSTEPS_) st_i(&out[bb*NSTEPS_ + lcn], bi);
                        st_i(&out[B_*NSTEPS_ + bb], lcn);
                        nl = bi;
                        sav += 1;
                    }
                    if (sav >= MAXSYM_) { tiv += 1; sav = 0; }
                    nw = ((unsigned long long)(s+1) << 32)
                       | ((unsigned long long)(lcn & 511) << 19)
                       | ((unsigned long long)(sav & 7) << 16)
                       | ((unsigned long long)((nl+1) & 31) << 11)
                       | ((unsigned long long)(tiv & 511) << 2)
                       | 2ULL | (unsigned long long)notb;
                }
                st_u64(&wq[bb], nw);
            }
        }
    }
}

extern "C" void kernel_launch(void* const* d_in, const int* in_sizes, int n_in,
                              void* d_out, int out_size, void* d_ws, size_t ws_size,
                              hipStream_t stream) {
    const float* x    = (const float*)d_in[0];
    const int*   olen = (const int*)d_in[1];
    const float* emb  = (const float*)d_in[2];
    const float* Wi0  = (const float*)d_in[3];
    const float* Wh0  = (const float*)d_in[4];
    const float* b0   = (const float*)d_in[5];
    const float* Wi1  = (const float*)d_in[6];
    const float* Wh1  = (const float*)d_in[7];
    const float* b1   = (const float*)d_in[8];
    const float* Wj1  = (const float*)d_in[9];
    const float* bj1  = (const float*)d_in[10];
    const float* Wj2  = (const float*)d_in[11];
    const float* bj2  = (const float*)d_in[12];
    float* ws = (float*)d_ws;
    int* out = (int*)d_out;

    hipLaunchKernelGGL(k_init, dim3(256), dim3(256), 0, stream, ws, out);
    hipLaunchKernelGGL(k_we,   dim3(28*5), dim3(256), 0, stream, emb, Wi0, ws);
    hipLaunchKernelGGL(k_fpre, dim3(T_*8), dim3(256), 0, stream, x, Wj1, bj1, ws);
    hipLaunchKernelGGL(k_decode, dim3(GDEC), dim3(BDEC), 0, stream,
                       olen, Wh0, b0, Wi1, Wh1, b1, Wj1, Wj2, bj2, ws, out);
}

// Round 6
// 8347.775 us; speedup vs baseline: 2.6697x; 1.0445x over previous
//
#include <hip/hip_runtime.h>
#include <math.h>

#define B_ 32
#define T_ 48
#define ENC_ 1024
#define PRED_ 320
#define G4P (4*PRED_)        // 1280
#define JH_ 512
#define NJ_ (ENC_+PRED_)     // 1344
#define VOCAB_ 29
#define BLANK_ 28
#define MAXSYM_ 6
#define NSTEPS_ (T_*MAXSYM_) // 288
#define GDEC 80
#define BDEC 512
#define NJB 32               // joint blocks, 16 v-cols each

// ---- workspace layout (float indices) ----
#define FPRE_OFF 0                       // 786432
#define WE_OFF   786432                  // 35840
#define H0C_OFF  822272                  // 10240  h0 candidates [k][b]
#define H1C_OFF  832512                  // 10240  h1 candidates [k][b]
#define PL_OFF   842752                  // 2*32*1024 partial logits (parity)
#define INT_OFF  908288                  // int-index base into (int*)ws
#define TA_I (INT_OFF + 0)               // 80 tags, stride 16 (own line)
#define TB_I (INT_OFF + 1280)
#define TC_I (INT_OFF + 2560)            // 32 tags
#define TD_I (INT_OFF + 3072)            // 80 decision tags
#define NTAGS 4352

__device__ __forceinline__ float sigm(float v) { return 1.0f / (1.0f + expf(-v)); }

__device__ __forceinline__ int  ld_i(const int* p)   { return __hip_atomic_load((int*)p, __ATOMIC_RELAXED, __HIP_MEMORY_SCOPE_AGENT); }
__device__ __forceinline__ void st_i(int* p, int v)  { __hip_atomic_store(p, v, __ATOMIC_RELAXED, __HIP_MEMORY_SCOPE_AGENT); }
__device__ __forceinline__ float ld_f(const float* p){ return __hip_atomic_load((float*)p, __ATOMIC_RELAXED, __HIP_MEMORY_SCOPE_AGENT); }
__device__ __forceinline__ void st_f(float* p, float v){ __hip_atomic_store(p, v, __ATOMIC_RELAXED, __HIP_MEMORY_SCOPE_AGENT); }

// ---------------- init ----------------
__global__ void k_init(float* __restrict__ ws, int* __restrict__ out) {
    int idx = blockIdx.x * blockDim.x + threadIdx.x;
    int stride = gridDim.x * blockDim.x;
    int* wi = (int*)ws;
    for (int i = idx; i < NTAGS; i += stride) wi[TA_I + i] = 0;
    for (int i = idx; i < B_*NSTEPS_; i += stride) out[i] = -1;  // lt
    if (idx < 32) out[B_*NSTEPS_ + idx] = 0;                     // lc
}

// ---------------- WE = emb @ Wi0^T  (28 x 1280) ----------------
__global__ __launch_bounds__(256) void k_we(const float* __restrict__ emb,
                                            const float* __restrict__ Wi0,
                                            float* __restrict__ ws) {
    __shared__ float es[PRED_];
    int l = blockIdx.x / 5;
    int rq = blockIdx.x % 5;
    int t = threadIdx.x;
    if (t < PRED_) es[t] = emb[l*PRED_ + t];
    if (t + 256 < PRED_) es[t + 256] = emb[l*PRED_ + t + 256];
    __syncthreads();
    int r = rq*256 + t;
    const float4* wr = (const float4*)(Wi0 + (size_t)r*PRED_);
    float acc = 0.0f;
    #pragma unroll 4
    for (int k4 = 0; k4 < PRED_/4; ++k4) {
        float4 w = wr[k4];
        acc += w.x*es[4*k4] + w.y*es[4*k4+1] + w.z*es[4*k4+2] + w.w*es[4*k4+3];
    }
    ws[WE_OFF + l*G4P + r] = acc;
}

// ---------------- Fpre[b][t][j] = x[b,t]·Wj1[j,:1024] + bj1[j] ----------------
__global__ __launch_bounds__(256) void k_fpre(const float* __restrict__ x,
                                              const float* __restrict__ Wj1,
                                              const float* __restrict__ bj1,
                                              float* __restrict__ ws) {
    __shared__ float As[B_][129];
    __shared__ float Bs[64][129];
    int tt = blockIdx.x >> 3;
    int jb = blockIdx.x & 7;
    int tid = threadIdx.x;
    int b = tid >> 3, jq = tid & 7;
    float acc[8] = {0,0,0,0,0,0,0,0};
    for (int kc = 0; kc < ENC_; kc += 128) {
        for (int i = tid; i < B_*128; i += 256) {
            int bb = i >> 7, kk = i & 127;
            As[bb][kk] = x[((size_t)bb*T_ + tt)*ENC_ + kc + kk];
        }
        for (int i = tid; i < 64*128; i += 256) {
            int jj = i >> 7, kk = i & 127;
            Bs[jj][kk] = Wj1[((size_t)(jb*64 + jj))*NJ_ + kc + kk];
        }
        __syncthreads();
        for (int kk = 0; kk < 128; ++kk) {
            float a = As[b][kk];
            #pragma unroll
            for (int u = 0; u < 8; ++u) acc[u] += a * Bs[jq*8 + u][kk];
        }
        __syncthreads();
    }
    #pragma unroll
    for (int u = 0; u < 8; ++u) {
        int j = jb*64 + jq*8 + u;
        ws[FPRE_OFF + ((size_t)b*T_ + tt)*JH_ + j] = acc[u] + bj1[j];
    }
}

// ---------------- persistent decode ----------------
__global__ __launch_bounds__(BDEC) void k_decode(
    const int* __restrict__ out_lens,
    const float* __restrict__ Wh0, const float* __restrict__ b0,
    const float* __restrict__ Wi1, const float* __restrict__ Wh1,
    const float* __restrict__ b1,
    const float* __restrict__ Wj1,
    const float* __restrict__ Wj2, const float* __restrict__ bj2,
    float* __restrict__ ws, int* __restrict__ out)
{
    float* H0C = ws + H0C_OFF;
    float* H1C = ws + H1C_OFF;
    float* PL  = ws + PL_OFF;
    const float* WE = ws + WE_OFF;
    const float* FP = ws + FPRE_OFF;
    int* wi = (int*)ws;
    int* tagA = wi + TA_I;
    int* tagB = wi + TB_I;
    int* tagC = wi + TC_I;
    int* tagD = wi + TD_I;

    __shared__ __align__(16) float wh0_s[16][PRED_];   // 20 KB
    __shared__ __align__(16) float wi1_s[16][PRED_];   // 20 KB
    __shared__ __align__(16) float wt_s[16][PRED_];    // 20 KB (blocks<32)
    __shared__ float hs0[B_*321];                      // 41 KB  h0 state/cand
    __shared__ float hs1[B_*321];                      // 41 KB  h1 state/cand
    __shared__ float c0cur[128], c0cand[128], c1cur[128], c1cand[128];
    __shared__ float jg_c[B_*16];                      // jg cache [b][v]
    __shared__ float wj2_s[VOCAB_*16];                 // [l][v]
    __shared__ float we_s[28][16];
    __shared__ float b0_s[16], b1_s[16];
    __shared__ float bj2_s[VOCAB_];
    __shared__ float parts[2048];                      // S1/S2 partials; hid; reduce
    __shared__ int ti_l[32], last_l[32], sa_l[32], lc_l[32];
    __shared__ int olen_s[32];
    __shared__ unsigned s_masks[2];

    const int tid = threadIdx.x;
    const int blk = blockIdx.x;
    const int j0  = blk * 4;

    // ---- one-time preload (read-only, normally cached) ----
    for (int i = tid; i < 16*PRED_; i += BDEC) {
        int r = i / PRED_, c = i % PRED_;
        int g = r >> 2, jl = r & 3;
        wh0_s[r][c] = Wh0[((size_t)(g*PRED_ + j0 + jl))*PRED_ + c];
        wi1_s[r][c] = Wi1[((size_t)(g*PRED_ + j0 + jl))*PRED_ + c];
    }
    if (blk < NJB) {
        for (int i = tid; i < 16*PRED_; i += BDEC) {
            int v = i / PRED_, k = i % PRED_;
            wt_s[v][k] = Wj1[((size_t)(blk*16 + v))*NJ_ + ENC_ + k];
        }
        for (int i = tid; i < VOCAB_*16; i += BDEC) {
            int l = i >> 4, v = i & 15;
            wj2_s[i] = Wj2[(size_t)l*JH_ + blk*16 + v];
        }
    }
    for (int i = tid; i < 28*16; i += BDEC) {
        int ls = i >> 4, r = i & 15;
        int g = r >> 2, jl = r & 3;
        we_s[ls][r] = WE[(size_t)ls*G4P + g*PRED_ + j0 + jl];
    }
    if (tid < 16) {
        int g = tid >> 2, jl = tid & 3;
        b0_s[tid] = b0[g*PRED_ + j0 + jl];
        b1_s[tid] = b1[g*PRED_ + j0 + jl];
    }
    if (tid < VOCAB_) bj2_s[tid] = bj2[tid];
    if (tid < 32) {
        olen_s[tid] = out_lens[tid];
        ti_l[tid] = 0; last_l[tid] = -1; sa_l[tid] = 0; lc_l[tid] = 0;
    }
    for (int i = tid; i < B_*321; i += BDEC) { hs0[i] = 0.f; hs1[i] = 0.f; }
    if (tid < 128) { c0cur[tid]=0.f; c0cand[tid]=0.f; c1cur[tid]=0.f; c1cand[tid]=0.f; }
    __syncthreads();

    const int b  = tid & 31;
    const int jl = (tid >> 5) & 3;
    const int ks = tid >> 7;       // 0..3
    unsigned nbm = 0xffffffffu, actm = 0xffffffffu;

    for (int s = 0; s < NSTEPS_; ++s) {
        const int par = s & 1;

        if (nbm) {
            // ================= S1: LSTM0 (LDS-resident operands) =================
            if ((nbm >> b) & 1) {
                const float* hrow = &hs0[b*321];
                int k0 = ks * 80;
                float a0=0.f, a1=0.f, a2=0.f, a3=0.f;
                #pragma unroll 4
                for (int kk = k0; kk < k0 + 80; kk += 4) {
                    float h0v = hrow[kk+0], h1v = hrow[kk+1];
                    float h2v = hrow[kk+2], h3v = hrow[kk+3];
                    float4 w0 = *(const float4*)&wh0_s[0*4+jl][kk];
                    float4 w1 = *(const float4*)&wh0_s[1*4+jl][kk];
                    float4 w2 = *(const float4*)&wh0_s[2*4+jl][kk];
                    float4 w3 = *(const float4*)&wh0_s[3*4+jl][kk];
                    a0 += w0.x*h0v + w0.y*h1v + w0.z*h2v + w0.w*h3v;
                    a1 += w1.x*h0v + w1.y*h1v + w1.z*h2v + w1.w*h3v;
                    a2 += w2.x*h0v + w2.y*h1v + w2.z*h2v + w2.w*h3v;
                    a3 += w3.x*h0v + w3.y*h1v + w3.z*h2v + w3.w*h3v;
                }
                parts[((0*4+ks)*4+jl)*32+b] = a0;
                parts[((1*4+ks)*4+jl)*32+b] = a1;
                parts[((2*4+ks)*4+jl)*32+b] = a2;
                parts[((3*4+ks)*4+jl)*32+b] = a3;
            }
            __syncthreads();
            if (tid < 128) {
                int bb = tid & 31, jj = tid >> 5;
                if ((nbm >> bb) & 1) {
                    int ls = last_l[bb];
                    float gt[4];
                    #pragma unroll
                    for (int g4 = 0; g4 < 4; ++g4) {
                        float v = parts[((g4*4+0)*4+jj)*32+bb] + parts[((g4*4+1)*4+jj)*32+bb]
                                + parts[((g4*4+2)*4+jj)*32+bb] + parts[((g4*4+3)*4+jj)*32+bb];
                        v += b0_s[g4*4+jj];
                        if (ls >= 0) v += we_s[ls][g4*4+jj];
                        gt[g4] = v;
                    }
                    float cold = c0cur[tid];
                    float cn = sigm(gt[1])*cold + sigm(gt[0])*tanhf(gt[2]);
                    float hn = sigm(gt[3])*tanhf(cn);
                    c0cand[tid] = cn;
                    st_f(&H0C[(j0+jj)*32 + bb], hn);
                }
            }
            __syncthreads();   // drain candidate stores
            if (tid == 0) st_i(&tagA[blk*16], s + 1);
            if (tid < GDEC) { while (ld_i(&tagA[tid*16]) < s + 1) __builtin_amdgcn_s_sleep(1); }
            __syncthreads();
            for (int i = tid; i < B_*PRED_; i += BDEC) {
                int bb = i & 31, kk = i >> 5;
                if ((nbm >> bb) & 1) hs0[bb*321 + kk] = ld_f(&H0C[kk*32 + bb]);
            }
            __syncthreads();

            // ================= S2: LSTM1 =================
            if ((nbm >> b) & 1) {
                const float* hxr = &hs0[b*321];   // h0 candidate
                const float* hhr = &hs1[b*321];   // h1 current
                const float* wh1r0 = Wh1 + ((size_t)(0*PRED_ + j0 + jl))*PRED_;
                const float* wh1r1 = Wh1 + ((size_t)(1*PRED_ + j0 + jl))*PRED_;
                const float* wh1r2 = Wh1 + ((size_t)(2*PRED_ + j0 + jl))*PRED_;
                const float* wh1r3 = Wh1 + ((size_t)(3*PRED_ + j0 + jl))*PRED_;
                int k0 = ks * 80;
                float a0=0.f, a1=0.f, a2=0.f, a3=0.f;
                #pragma unroll 2
                for (int kk = k0; kk < k0 + 80; kk += 4) {
                    float x0 = hxr[kk+0], x1 = hxr[kk+1], x2 = hxr[kk+2], x3 = hxr[kk+3];
                    float y0 = hhr[kk+0], y1 = hhr[kk+1], y2 = hhr[kk+2], y3 = hhr[kk+3];
                    float4 wa0 = *(const float4*)&wi1_s[0*4+jl][kk];
                    float4 wa1 = *(const float4*)&wi1_s[1*4+jl][kk];
                    float4 wa2 = *(const float4*)&wi1_s[2*4+jl][kk];
                    float4 wa3 = *(const float4*)&wi1_s[3*4+jl][kk];
                    float4 wb0 = *(const float4*)(wh1r0 + kk);
                    float4 wb1 = *(const float4*)(wh1r1 + kk);
                    float4 wb2 = *(const float4*)(wh1r2 + kk);
                    float4 wb3 = *(const float4*)(wh1r3 + kk);
                    a0 += wa0.x*x0+wa0.y*x1+wa0.z*x2+wa0.w*x3 + wb0.x*y0+wb0.y*y1+wb0.z*y2+wb0.w*y3;
                    a1 += wa1.x*x0+wa1.y*x1+wa1.z*x2+wa1.w*x3 + wb1.x*y0+wb1.y*y1+wb1.z*y2+wb1.w*y3;
                    a2 += wa2.x*x0+wa2.y*x1+wa2.z*x2+wa2.w*x3 + wb2.x*y0+wb2.y*y1+wb2.z*y2+wb2.w*y3;
                    a3 += wa3.x*x0+wa3.y*x1+wa3.z*x2+wa3.w*x3 + wb3.x*y0+wb3.y*y1+wb3.z*y2+wb3.w*y3;
                }
                parts[((0*4+ks)*4+jl)*32+b] = a0;
                parts[((1*4+ks)*4+jl)*32+b] = a1;
                parts[((2*4+ks)*4+jl)*32+b] = a2;
                parts[((3*4+ks)*4+jl)*32+b] = a3;
            }
            __syncthreads();
            if (tid < 128) {
                int bb = tid & 31, jj = tid >> 5;
                if ((nbm >> bb) & 1) {
                    float gt[4];
                    #pragma unroll
                    for (int g4 = 0; g4 < 4; ++g4) {
                        float v = parts[((g4*4+0)*4+jj)*32+bb] + parts[((g4*4+1)*4+jj)*32+bb]
                                + parts[((g4*4+2)*4+jj)*32+bb] + parts[((g4*4+3)*4+jj)*32+bb];
                        v += b1_s[g4*4+jj];
                        gt[g4] = v;
                    }
                    float cold = c1cur[tid];
                    float cn = sigm(gt[1])*cold + sigm(gt[0])*tanhf(gt[2]);
                    float hn = sigm(gt[3])*tanhf(cn);
                    c1cand[tid] = cn;
                    st_f(&H1C[(j0+jj)*32 + bb], hn);
                }
            }
            __syncthreads();
            if (tid == 0) st_i(&tagB[blk*16], s + 1);
            if (tid < GDEC) { while (ld_i(&tagB[tid*16]) < s + 1) __builtin_amdgcn_s_sleep(1); }
            __syncthreads();
            for (int i = tid; i < B_*PRED_; i += BDEC) {
                int bb = i & 31, kk = i >> 5;
                if ((nbm >> bb) & 1) hs1[bb*321 + kk] = ld_f(&H1C[kk*32 + bb]);
            }
            __syncthreads();
        }

        // ===== S3a: joint (16 v-cols per block, blocks 0..31) + publish PL =====
        if (blk < NJB) {
            if (!nbm) {
                // blank path: PL[par] overwrite needs step-(s-2) readers done
                if (tid < GDEC) { while (ld_i(&tagD[tid*16]) < s - 1) __builtin_amdgcn_s_sleep(1); }
                __syncthreads();
            }
            const int b3 = tid & 31, v3 = tid >> 5;   // v3: 0..15
            if (nbm && ((nbm >> b3) & 1)) {
                const float* hrow = &hs1[b3*321];
                float p = 0.f;
                #pragma unroll 4
                for (int kk = 0; kk < PRED_; kk += 4) {
                    float4 w4 = *(const float4*)&wt_s[v3][kk];
                    p += w4.x*hrow[kk+0] + w4.y*hrow[kk+1]
                       + w4.z*hrow[kk+2] + w4.w*hrow[kk+3];
                }
                jg_c[b3*16 + v3] = p;
            }
            if ((actm >> b3) & 1) {
                int tm = min(ti_l[b3], T_ - 1);
                float hv = FP[((size_t)b3*T_ + tm)*JH_ + blk*16 + v3] + jg_c[b3*16 + v3];
                parts[b3*16 + v3] = fmaxf(hv, 0.f);
            }
            __syncthreads();
            {
                float* plb = PL + (size_t)(par*NJB + blk)*1024;
                #pragma unroll
                for (int u = 0; u < 2; ++u) {
                    int slot = tid + u*512;
                    int bb = slot >> 5, l = slot & 31;
                    if (l < VOCAB_ && ((actm >> bb) & 1)) {
                        const float* w = &wj2_s[l*16];
                        const float* h = &parts[bb*16];
                        float acc = 0.f;
                        #pragma unroll
                        for (int v = 0; v < 16; ++v) acc += w[v]*h[v];
                        st_f(&plb[slot], acc);
                    }
                }
            }
            __syncthreads();   // drain PL stores
            if (tid == 0) st_i(&tagC[blk*16], s + 1);
        }

        // ===== hop C: poll + read partials + local reduce + local decision =====
        if (tid < NJB) { while (ld_i(&tagC[tid*16]) < s + 1) __builtin_amdgcn_s_sleep(1); }
        __syncthreads();
        {
            const float* plp = PL + (size_t)par*NJB*1024;
            float a0 = 0.f, a1 = 0.f;
            #pragma unroll
            for (int q = 0; q < NJB; ++q) {
                a0 += ld_f(&plp[q*1024 + tid]);
                a1 += ld_f(&plp[q*1024 + tid + 512]);
            }
            parts[tid] = a0;
            parts[tid + 512] = a1;
        }
        __syncthreads();
        if (tid < 64) {
            int nb = 0, act = 0;
            if (tid < 32 && ((actm >> tid) & 1)) {
                const int bb = tid;
                float best = -1e30f; int bi = 0;
                for (int l = 0; l < VOCAB_; ++l) {
                    float v = parts[bb*32 + l] + bj2_s[l];
                    if (v > best) { best = v; bi = l; }
                }
                const int blankness = (bi == BLANK_) ? 1 : 0;
                int tiv = ti_l[bb] + blankness;
                if (tiv >= olen_s[bb]) {
                    ti_l[bb] = tiv;          // frozen: nb=0, act=0
                } else {
                    int notb = 1 - blankness;
                    int sav = blankness ? 0 : sa_l[bb];
                    int nl = last_l[bb];
                    int lcn = lc_l[bb];
                    if (notb) {
                        lcn += 1;
                        if (blk == bb) {
                            if (lcn < NSTEPS_) st_i(&out[bb*NSTEPS_ + lcn], bi);
                            st_i(&out[B_*NSTEPS_ + bb], lcn);
                        }
                        nl = bi;
                        sav += 1;
                    }
                    if (sav >= MAXSYM_) { tiv += 1; sav = 0; }
                    ti_l[bb] = tiv; sa_l[bb] = sav; last_l[bb] = nl; lc_l[bb] = lcn;
                    nb = notb; act = 1;
                }
            }
            unsigned long long mnb  = __ballot(nb != 0);
            unsigned long long mact = __ballot(act != 0);
            if (tid == 0) {
                s_masks[0] = (unsigned)(mnb & 0xffffffffULL);
                s_masks[1] = (unsigned)(mact & 0xffffffffULL);
            }
        }
        __syncthreads();
        nbm = s_masks[0]; actm = s_masks[1];
        if (tid == 0) st_i(&tagD[blk*16], s + 1);
        if (!actm) break;
        // commit accepted c-candidates for next step
        if (tid < 128) {
            int bb = tid & 31;
            if ((nbm >> bb) & 1) { c0cur[tid] = c0cand[tid]; c1cur[tid] = c1cand[tid]; }
        }
        __syncthreads();
    }
}

extern "C" void kernel_launch(void* const* d_in, const int* in_sizes, int n_in,
                              void* d_out, int out_size, void* d_ws, size_t ws_size,
                              hipStream_t stream) {
    const float* x    = (const float*)d_in[0];
    const int*   olen = (const int*)d_in[1];
    const float* emb  = (const float*)d_in[2];
    const float* Wi0  = (const float*)d_in[3];
    const float* Wh0  = (const float*)d_in[4];
    const float* b0   = (const float*)d_in[5];
    const float* Wi1  = (const float*)d_in[6];
    const float* Wh1  = (const float*)d_in[7];
    const float* b1   = (const float*)d_in[8];
    const float* Wj1  = (const float*)d_in[9];
    const float* bj1  = (const float*)d_in[10];
    const float* Wj2  = (const float*)d_in[11];
    const float* bj2  = (const float*)d_in[12];
    float* ws = (float*)d_ws;
    int* out = (int*)d_out;

    hipLaunchKernelGGL(k_init, dim3(256), dim3(256), 0, stream, ws, out);
    hipLaunchKernelGGL(k_we,   dim3(28*5), dim3(256), 0, stream, emb, Wi0, ws);
    hipLaunchKernelGGL(k_fpre, dim3(T_*8), dim3(256), 0, stream, x, Wj1, bj1, ws);
    hipLaunchKernelGGL(k_decode, dim3(GDEC), dim3(BDEC), 0, stream,
                       olen, Wh0, b0, Wi1, Wh1, b1, Wj1, Wj2, bj2, ws, out);
}

// Round 8
// 6451.736 us; speedup vs baseline: 3.4543x; 1.2939x over previous
//
#include <hip/hip_runtime.h>
#include <math.h>

#define B_ 32
#define T_ 48
#define ENC_ 1024
#define PRED_ 320
#define JH_ 512
#define NJ_ 1344
#define VOCAB_ 29
#define BLANK_ 28
#define MAXSYM_ 6
#define NSTEPS_ 288
#define GDEC 80
#define BDEC 512
#define GB 16      // batch per group
#define GBLK 40    // blocks per group
#define JPB 8      // LSTM j-cols per block
#define NJB 16     // joint blocks per group
#define VPB 32     // joint v-cols per joint block
#define HPAD 324   // padded h row

// ---- workspace layout (float indices) ----
#define FPRE_OFF 0                // 786432
#define WE_OFF   786432           // 28*1280
#define H0C_OFF  822272           // + g*5120   (16 b x 320, b-major)
#define H1C_OFF  832512           // + g*5120
#define PL_OFF   842752           // + g*16384 + par*8192 + jb*512 + gb*32 + l
#define INT_OFF  875520           // int region
// tags (ints rel INT_OFF), stride 16:
//   TA: g*640+i*16  TB: 1280+g*640+i*16  TC: 2560+g*256+i*16  TD: 3072+g*640+i*16
#define NTAGS 4352

__device__ __forceinline__ float sigm(float v) { return 1.0f / (1.0f + expf(-v)); }

__device__ __forceinline__ int  ld_i(const int* p)   { return __hip_atomic_load((int*)p, __ATOMIC_RELAXED, __HIP_MEMORY_SCOPE_AGENT); }
__device__ __forceinline__ void st_i(int* p, int v)  { __hip_atomic_store(p, v, __ATOMIC_RELAXED, __HIP_MEMORY_SCOPE_AGENT); }
__device__ __forceinline__ void st_f(float* p, float v){ __hip_atomic_store(p, v, __ATOMIC_RELAXED, __HIP_MEMORY_SCOPE_AGENT); }

// coherent 16B loads (bypass L1/L2, served at coherence point), wait folded in.
// Multi-load single-asm-block with early-clobber outputs: legal on gfx950.
__device__ __forceinline__ void ldc4_2(const float* p0, const float* p1,
                                       float4& r0, float4& r1) {
    asm volatile("global_load_dwordx4 %0, %2, off sc0 sc1\n\t"
                 "global_load_dwordx4 %1, %3, off sc0 sc1\n\t"
                 "s_waitcnt vmcnt(0)"
                 : "=&v"(r0), "=&v"(r1)
                 : "v"(p0), "v"(p1)
                 : "memory");
}
__device__ __forceinline__ void ldc4_3(const float* p0, const float* p1, const float* p2,
                                       float4& r0, float4& r1, float4& r2) {
    asm volatile("global_load_dwordx4 %0, %3, off sc0 sc1\n\t"
                 "global_load_dwordx4 %1, %4, off sc0 sc1\n\t"
                 "global_load_dwordx4 %2, %5, off sc0 sc1\n\t"
                 "s_waitcnt vmcnt(0)"
                 : "=&v"(r0), "=&v"(r1), "=&v"(r2)
                 : "v"(p0), "v"(p1), "v"(p2)
                 : "memory");
}
__device__ __forceinline__ void ldc4_4(const float* p0, const float* p1,
                                       const float* p2, const float* p3,
                                       float4& r0, float4& r1, float4& r2, float4& r3) {
    asm volatile("global_load_dwordx4 %0, %4, off sc0 sc1\n\t"
                 "global_load_dwordx4 %1, %5, off sc0 sc1\n\t"
                 "global_load_dwordx4 %2, %6, off sc0 sc1\n\t"
                 "global_load_dwordx4 %3, %7, off sc0 sc1\n\t"
                 "s_waitcnt vmcnt(0)"
                 : "=&v"(r0), "=&v"(r1), "=&v"(r2), "=&v"(r3)
                 : "v"(p0), "v"(p1), "v"(p2), "v"(p3)
                 : "memory");
}

// ---------------- init ----------------
__global__ void k_init(float* __restrict__ ws, int* __restrict__ out) {
    int idx = blockIdx.x * blockDim.x + threadIdx.x;
    int stride = gridDim.x * blockDim.x;
    int* wi = (int*)ws;
    for (int i = idx; i < NTAGS; i += stride) wi[INT_OFF + i] = 0;
    for (int i = idx; i < B_*NSTEPS_; i += stride) out[i] = -1;  // lt
    if (idx < B_) out[B_*NSTEPS_ + idx] = 0;                     // lc
}

// ---------------- WE = emb @ Wi0^T  (28 x 1280) ----------------
__global__ __launch_bounds__(256) void k_we(const float* __restrict__ emb,
                                            const float* __restrict__ Wi0,
                                            float* __restrict__ ws) {
    __shared__ float es[PRED_];
    int l = blockIdx.x / 5;
    int rq = blockIdx.x % 5;
    int t = threadIdx.x;
    if (t < PRED_) es[t] = emb[l*PRED_ + t];
    if (t + 256 < PRED_) es[t + 256] = emb[l*PRED_ + t + 256];
    __syncthreads();
    int r = rq*256 + t;
    const float4* wr = (const float4*)(Wi0 + (size_t)r*PRED_);
    float acc = 0.0f;
    #pragma unroll 4
    for (int k4 = 0; k4 < PRED_/4; ++k4) {
        float4 w = wr[k4];
        acc += w.x*es[4*k4] + w.y*es[4*k4+1] + w.z*es[4*k4+2] + w.w*es[4*k4+3];
    }
    ws[WE_OFF + l*(4*PRED_) + r] = acc;
}

// ---------------- Fpre[b][t][j] = x[b,t]·Wj1[j,:1024] + bj1[j] ----------------
__global__ __launch_bounds__(256) void k_fpre(const float* __restrict__ x,
                                              const float* __restrict__ Wj1,
                                              const float* __restrict__ bj1,
                                              float* __restrict__ ws) {
    __shared__ float As[B_][129];
    __shared__ float Bs[64][129];
    int tt = blockIdx.x >> 3;
    int jb = blockIdx.x & 7;
    int tid = threadIdx.x;
    int b = tid >> 3, jq = tid & 7;
    float acc[8] = {0,0,0,0,0,0,0,0};
    for (int kc = 0; kc < ENC_; kc += 128) {
        for (int i = tid; i < B_*128; i += 256) {
            int bb = i >> 7, kk = i & 127;
            As[bb][kk] = x[((size_t)bb*T_ + tt)*ENC_ + kc + kk];
        }
        for (int i = tid; i < 64*128; i += 256) {
            int jj = i >> 7, kk = i & 127;
            Bs[jj][kk] = Wj1[((size_t)(jb*64 + jj))*NJ_ + kc + kk];
        }
        __syncthreads();
        for (int kk = 0; kk < 128; ++kk) {
            float a = As[b][kk];
            #pragma unroll
            for (int u = 0; u < 8; ++u) acc[u] += a * Bs[jq*8 + u][kk];
        }
        __syncthreads();
    }
    #pragma unroll
    for (int u = 0; u < 8; ++u) {
        int j = jb*64 + jq*8 + u;
        ws[FPRE_OFF + ((size_t)b*T_ + tt)*JH_ + j] = acc[u] + bj1[j];
    }
}

// ---------------- persistent decode: 2 independent batch-groups ----------------
__global__ __launch_bounds__(BDEC) void k_decode(
    const int* __restrict__ out_lens,
    const float* __restrict__ Wh0, const float* __restrict__ b0,
    const float* __restrict__ Wi1, const float* __restrict__ Wh1,
    const float* __restrict__ b1,
    const float* __restrict__ Wj1,
    const float* __restrict__ Wj2, const float* __restrict__ bj2,
    float* __restrict__ ws, int* __restrict__ out)
{
    const int tid = threadIdx.x;
    const int grp = blockIdx.x & 1;
    const int lb  = blockIdx.x >> 1;       // 0..39 group-local
    const int j0  = lb * JPB;              // LSTM col base
    const int v0  = lb * VPB;              // joint col base (lb<16)
    const int bb0 = grp * GB;              // global batch base

    float* H0Cg = ws + H0C_OFF + grp*5120;
    float* H1Cg = ws + H1C_OFF + grp*5120;
    float* PLg  = ws + PL_OFF  + grp*16384;
    const float* WE = ws + WE_OFF;
    const float* FP = ws + FPRE_OFF;
    int* wi = (int*)ws;
    int* tagA = wi + INT_OFF + grp*640;
    int* tagB = wi + INT_OFF + 1280 + grp*640;
    int* tagC = wi + INT_OFF + 2560 + grp*256;
    int* tagD = wi + INT_OFF + 3072 + grp*640;

    // ---- LDS ----
    __shared__ __align__(16) float wi1_s[32*HPAD];   // 40.5 KB (padded rows)
    __shared__ __align__(16) float hs0[GB*HPAD];     // 20.7 KB h0 candidates
    __shared__ __align__(16) float hs1[GB*HPAD];     // 20.7 KB h1 candidates
    __shared__ float P0a[32*GB], P0b[32*GB], P1s[32*GB];  // partial-GEMV caches
    __shared__ float parts[2048];
    __shared__ float c0cur[128], c0cand[128], c1cur[128], c1cand[128];
    __shared__ float we_s[28][32];
    __shared__ float b0_s[32], b1_s[32], bj2_s[VOCAB_];
    __shared__ float wj2t[VPB*33];                   // [v][l] transposed
    __shared__ float jg_c[VPB*GB];                   // [v][gb]
    __shared__ float hid_s[GB*33];                   // [gb][v]
    __shared__ float logits_s[GB*33];
    __shared__ int ti_l[GB], last_l[GB], sa_l[GB], lc_l[GB], olen_s[GB];
    __shared__ int nb_a[GB], act_a[GB];
    __shared__ unsigned s_masks[2];

    // ---- one-time preload ----
    for (int i = tid; i < 32*PRED_; i += BDEC) {
        int r = i / PRED_, c = i % PRED_;
        int g = r >> 3, jj = r & 7;
        wi1_s[r*HPAD + c] = Wi1[((size_t)(g*PRED_ + j0 + jj))*PRED_ + c];
    }
    if (lb < NJB) {
        for (int i = tid; i < VPB*32; i += BDEC) {
            int v = i >> 5, l = i & 31;
            wj2t[v*33 + l] = (l < VOCAB_) ? Wj2[(size_t)l*JH_ + v0 + v] : 0.f;
        }
    }
    for (int i = tid; i < 28*32; i += BDEC) {
        int ls = i >> 5, r = i & 31;
        int g = r >> 3, jj = r & 7;
        we_s[ls][r] = WE[(size_t)ls*(4*PRED_) + g*PRED_ + j0 + jj];
    }
    if (tid < 32) {
        int g = tid >> 3, jj = tid & 7;
        b0_s[tid] = b0[g*PRED_ + j0 + jj];
        b1_s[tid] = b1[g*PRED_ + j0 + jj];
    }
    if (tid < VOCAB_) bj2_s[tid] = bj2[tid];
    if (tid < GB) {
        olen_s[tid] = out_lens[bb0 + tid];
        ti_l[tid] = 0; last_l[tid] = -1; sa_l[tid] = 0; lc_l[tid] = 0;
    }
    for (int i = tid; i < GB*HPAD; i += BDEC) { hs0[i] = 0.f; hs1[i] = 0.f; }
    for (int i = tid; i < 32*GB; i += BDEC) P0a[i] = 0.f;
    if (tid < 128) { c0cur[tid]=0.f; c0cand[tid]=0.f; c1cur[tid]=0.f; c1cand[tid]=0.f; }
    __syncthreads();

    const int gb  = tid & 15;
    const int jl  = (tid >> 4) & 7;
    const int ks  = tid >> 7;         // 0..3 (k-chunks of 80)
    unsigned nbm = 0xffffu, actm = 0xffffu;

    for (int s = 0; s < NSTEPS_; ++s) {
        const int par = s & 1;

        if (nbm) {
            // ===== S1 finalize (pure LDS: P0a + WE[last] + b0) + publish =====
            if (tid < 128) {
                int g2 = tid & 15, jj = tid >> 4;
                if ((nbm >> g2) & 1) {
                    int ls = last_l[g2];
                    float gt[4];
                    #pragma unroll
                    for (int g = 0; g < 4; ++g) {
                        int r = g*8 + jj;
                        float v = P0a[r*GB + g2] + b0_s[r];
                        if (ls >= 0) v += we_s[ls][r];
                        gt[g] = v;
                    }
                    float cn = sigm(gt[1])*c0cur[tid] + sigm(gt[0])*tanhf(gt[2]);
                    float hn = sigm(gt[3])*tanhf(cn);
                    c0cand[tid] = cn;
                    st_f(&H0Cg[g2*PRED_ + j0 + jj], hn);
                }
            }
            __syncthreads();                 // drain publishes
            if (tid == 0) st_i(&tagA[lb*16], s + 1);

            // ===== P1 = Wh1 · h1cur (streamed weights; hides hopA wait) =====
            {
                const float* hr = &hs1[gb*HPAD];
                int k0 = ks * 80;
                float a0=0.f,a1=0.f,a2=0.f,a3=0.f;
                const float* w0 = Wh1 + ((size_t)(0*PRED_ + j0 + jl))*PRED_;
                const float* w1 = Wh1 + ((size_t)(1*PRED_ + j0 + jl))*PRED_;
                const float* w2 = Wh1 + ((size_t)(2*PRED_ + j0 + jl))*PRED_;
                const float* w3 = Wh1 + ((size_t)(3*PRED_ + j0 + jl))*PRED_;
                #pragma unroll 4
                for (int kk = k0; kk < k0 + 80; kk += 4) {
                    float4 h = *(const float4*)&hr[kk];
                    float4 q0 = *(const float4*)(w0 + kk);
                    float4 q1 = *(const float4*)(w1 + kk);
                    float4 q2 = *(const float4*)(w2 + kk);
                    float4 q3 = *(const float4*)(w3 + kk);
                    a0 += q0.x*h.x+q0.y*h.y+q0.z*h.z+q0.w*h.w;
                    a1 += q1.x*h.x+q1.y*h.y+q1.z*h.z+q1.w*h.w;
                    a2 += q2.x*h.x+q2.y*h.y+q2.z*h.z+q2.w*h.w;
                    a3 += q3.x*h.x+q3.y*h.y+q3.z*h.z+q3.w*h.w;
                }
                parts[((0*4+ks)*8+jl)*16+gb] = a0;
                parts[((1*4+ks)*8+jl)*16+gb] = a1;
                parts[((2*4+ks)*8+jl)*16+gb] = a2;
                parts[((3*4+ks)*8+jl)*16+gb] = a3;
            }
            __syncthreads();
            for (int i = tid; i < 32*GB; i += BDEC) {
                int r = i / GB, g2 = i % GB;
                P1s[r*GB + g2] = parts[((((r>>3)*4+0)*8)+(r&7))*16+g2]
                               + parts[((((r>>3)*4+1)*8)+(r&7))*16+g2]
                               + parts[((((r>>3)*4+2)*8)+(r&7))*16+g2]
                               + parts[((((r>>3)*4+3)*8)+(r&7))*16+g2];
            }
            __syncthreads();

            // ===== hopA: poll + x4 stage h0cand =====
            if (tid < GBLK) { while (ld_i(&tagA[tid*16]) < s+1) __builtin_amdgcn_s_sleep(1); }
            __syncthreads();
            {
                int i0 = tid, i1 = tid + 512, i2 = tid + 1024;
                float4 r0, r1, r2;
                bool h2 = (i2 < 1280);
                if (h2) ldc4_3(H0Cg+i0*4, H0Cg+i1*4, H0Cg+i2*4, r0, r1, r2);
                else    ldc4_2(H0Cg+i0*4, H0Cg+i1*4, r0, r1);
                int g0 = i0/80, o0 = (i0%80)*4;
                int g1 = i1/80, o1 = (i1%80)*4;
                if ((nbm >> g0) & 1) *(float4*)&hs0[g0*HPAD + o0] = r0;
                if ((nbm >> g1) & 1) *(float4*)&hs0[g1*HPAD + o1] = r1;
                if (h2) { int g2i = i2/80, o2 = (i2%80)*4;
                          if ((nbm >> g2i) & 1) *(float4*)&hs0[g2i*HPAD + o2] = r2; }
            }
            __syncthreads();

            // ===== S2: Wi1·h0cand (LDS) + P1 =====
            {
                const float* hr = &hs0[gb*HPAD];
                int k0 = ks * 80;
                float a0=0.f,a1=0.f,a2=0.f,a3=0.f;
                #pragma unroll 4
                for (int kk = k0; kk < k0 + 80; kk += 4) {
                    float4 h = *(const float4*)&hr[kk];
                    float4 q0 = *(const float4*)&wi1_s[(0*8+jl)*HPAD + kk];
                    float4 q1 = *(const float4*)&wi1_s[(1*8+jl)*HPAD + kk];
                    float4 q2 = *(const float4*)&wi1_s[(2*8+jl)*HPAD + kk];
                    float4 q3 = *(const float4*)&wi1_s[(3*8+jl)*HPAD + kk];
                    a0 += q0.x*h.x+q0.y*h.y+q0.z*h.z+q0.w*h.w;
                    a1 += q1.x*h.x+q1.y*h.y+q1.z*h.z+q1.w*h.w;
                    a2 += q2.x*h.x+q2.y*h.y+q2.z*h.z+q2.w*h.w;
                    a3 += q3.x*h.x+q3.y*h.y+q3.z*h.z+q3.w*h.w;
                }
                parts[((0*4+ks)*8+jl)*16+gb] = a0;
                parts[((1*4+ks)*8+jl)*16+gb] = a1;
                parts[((2*4+ks)*8+jl)*16+gb] = a2;
                parts[((3*4+ks)*8+jl)*16+gb] = a3;
            }
            __syncthreads();
            if (tid < 128) {
                int g2 = tid & 15, jj = tid >> 4;
                if ((nbm >> g2) & 1) {
                    float gt[4];
                    #pragma unroll
                    for (int g = 0; g < 4; ++g) {
                        int r = g*8 + jj;
                        gt[g] = parts[((g*4+0)*8+jj)*16+g2] + parts[((g*4+1)*8+jj)*16+g2]
                              + parts[((g*4+2)*8+jj)*16+g2] + parts[((g*4+3)*8+jj)*16+g2]
                              + P1s[r*GB + g2] + b1_s[r];
                    }
                    float cn = sigm(gt[1])*c1cur[tid] + sigm(gt[0])*tanhf(gt[2]);
                    float hn = sigm(gt[3])*tanhf(cn);
                    c1cand[tid] = cn;
                    st_f(&H1Cg[g2*PRED_ + j0 + jj], hn);
                }
            }
            __syncthreads();
            if (tid == 0) st_i(&tagB[lb*16], s + 1);

            // ===== hopB: poll + x4 stage h1cand =====
            if (tid < GBLK) { while (ld_i(&tagB[tid*16]) < s+1) __builtin_amdgcn_s_sleep(1); }
            __syncthreads();
            {
                int i0 = tid, i1 = tid + 512, i2 = tid + 1024;
                float4 r0, r1, r2;
                bool h2 = (i2 < 1280);
                if (h2) ldc4_3(H1Cg+i0*4, H1Cg+i1*4, H1Cg+i2*4, r0, r1, r2);
                else    ldc4_2(H1Cg+i0*4, H1Cg+i1*4, r0, r1);
                int g0 = i0/80, o0 = (i0%80)*4;
                int g1 = i1/80, o1 = (i1%80)*4;
                if ((nbm >> g0) & 1) *(float4*)&hs1[g0*HPAD + o0] = r0;
                if ((nbm >> g1) & 1) *(float4*)&hs1[g1*HPAD + o1] = r1;
                if (h2) { int g2i = i2/80, o2 = (i2%80)*4;
                          if ((nbm >> g2i) & 1) *(float4*)&hs1[g2i*HPAD + o2] = r2; }
            }
            __syncthreads();
        } else {
            // blank step: PL[par] overwrite needs step-(s-2) readers done
            if (lb < NJB) {
                if (tid < GBLK) { while (ld_i(&tagD[tid*16]) < s-1) __builtin_amdgcn_s_sleep(1); }
                __syncthreads();
            }
        }

        // ===== S3a: joint blocks: jg (if recomputed) + hid + partial logits =====
        if (lb < NJB) {
            {
                int v = tid >> 4, g2 = tid & 15;
                if (nbm && ((nbm >> g2) & 1)) {
                    const float* hr = &hs1[g2*HPAD];
                    const float* wt = Wj1 + ((size_t)(v0 + v))*NJ_ + ENC_;
                    float p = 0.f;
                    #pragma unroll 4
                    for (int kk = 0; kk < PRED_; kk += 4) {
                        float4 w4 = *(const float4*)(wt + kk);
                        float4 h  = *(const float4*)&hr[kk];
                        p += w4.x*h.x + w4.y*h.y + w4.z*h.z + w4.w*h.w;
                    }
                    jg_c[v*GB + g2] = p;
                }
                if ((actm >> g2) & 1) {
                    int tm = min(ti_l[g2], T_ - 1);
                    float hv = FP[((size_t)(bb0+g2)*T_ + tm)*JH_ + v0 + v] + jg_c[v*GB + g2];
                    hid_s[g2*33 + v] = fmaxf(hv, 0.f);
                }
            }
            __syncthreads();
            {
                int g2 = tid >> 5, l = tid & 31;
                const float* hb = &hid_s[g2*33];
                float acc = 0.f;
                #pragma unroll 8
                for (int v = 0; v < VPB; ++v) acc += wj2t[v*33 + l] * hb[v];
                st_f(&PLg[par*8192 + lb*512 + g2*32 + l], acc);
            }
            __syncthreads();
            if (tid == 0) st_i(&tagC[lb*16], s + 1);
        }

        // ===== P0b = Wh0 · h0cand (streamed; hides hopC wait) — nb-steps only =====
        if (nbm) {
            const float* hr = &hs0[gb*HPAD];
            int k0 = ks * 80;
            float a0=0.f,a1=0.f,a2=0.f,a3=0.f;
            const float* w0 = Wh0 + ((size_t)(0*PRED_ + j0 + jl))*PRED_;
            const float* w1 = Wh0 + ((size_t)(1*PRED_ + j0 + jl))*PRED_;
            const float* w2 = Wh0 + ((size_t)(2*PRED_ + j0 + jl))*PRED_;
            const float* w3 = Wh0 + ((size_t)(3*PRED_ + j0 + jl))*PRED_;
            #pragma unroll 4
            for (int kk = k0; kk < k0 + 80; kk += 4) {
                float4 h = *(const float4*)&hr[kk];
                float4 q0 = *(const float4*)(w0 + kk);
                float4 q1 = *(const float4*)(w1 + kk);
                float4 q2 = *(const float4*)(w2 + kk);
                float4 q3 = *(const float4*)(w3 + kk);
                a0 += q0.x*h.x+q0.y*h.y+q0.z*h.z+q0.w*h.w;
                a1 += q1.x*h.x+q1.y*h.y+q1.z*h.z+q1.w*h.w;
                a2 += q2.x*h.x+q2.y*h.y+q2.z*h.z+q2.w*h.w;
                a3 += q3.x*h.x+q3.y*h.y+q3.z*h.z+q3.w*h.w;
            }
            __syncthreads();
            parts[((0*4+ks)*8+jl)*16+gb] = a0;
            parts[((1*4+ks)*8+jl)*16+gb] = a1;
            parts[((2*4+ks)*8+jl)*16+gb] = a2;
            parts[((3*4+ks)*8+jl)*16+gb] = a3;
            __syncthreads();
            for (int i = tid; i < 32*GB; i += BDEC) {
                int r = i / GB, g2 = i % GB;
                P0b[r*GB + g2] = parts[((((r>>3)*4+0)*8)+(r&7))*16+g2]
                               + parts[((((r>>3)*4+1)*8)+(r&7))*16+g2]
                               + parts[((((r>>3)*4+2)*8)+(r&7))*16+g2]
                               + parts[((((r>>3)*4+3)*8)+(r&7))*16+g2];
            }
            __syncthreads();
        }

        // ===== hopC: poll + x4 PL reduce (identical order in every block) =====
        if (tid < NJB) { while (ld_i(&tagC[tid*16]) < s+1) __builtin_amdgcn_s_sleep(1); }
        __syncthreads();
        {
            int sg = tid & 127, jq = tid >> 7;       // jq 0..3 (4 jb each)
            int g2 = sg >> 3, l4 = (sg & 7) * 4;
            const float* pb = PLg + par*8192 + (jq*4)*512 + g2*32 + l4;
            float4 r0, r1, r2, r3;
            ldc4_4(pb, pb + 512, pb + 1024, pb + 1536, r0, r1, r2, r3);
            float4 sm;
            sm.x = ((r0.x + r1.x) + r2.x) + r3.x;
            sm.y = ((r0.y + r1.y) + r2.y) + r3.y;
            sm.z = ((r0.z + r1.z) + r2.z) + r3.z;
            sm.w = ((r0.w + r1.w) + r2.w) + r3.w;
            *(float4*)&parts[(jq*128 + sg)*4] = sm;
        }
        __syncthreads();
        if (tid < 128) {
            int g2 = tid >> 3, l4 = (tid & 7) * 4;
            #pragma unroll
            for (int e = 0; e < 4; ++e) {
                int l = l4 + e;
                float v = ((parts[(0*128+tid)*4+e] + parts[(1*128+tid)*4+e])
                         + parts[(2*128+tid)*4+e]) + parts[(3*128+tid)*4+e];
                logits_s[g2*33 + l] = (l < VOCAB_) ? (v + bj2_s[l]) : -1e30f;
            }
        }
        __syncthreads();

        // ===== local redundant decide =====
        if (tid < GB) {
            int nb = 0, act = 0;
            if ((actm >> tid) & 1) {
                const int g2 = tid;
                float best = -1e30f; int bi = 0;
                for (int l = 0; l < VOCAB_; ++l) {
                    float v = logits_s[g2*33 + l];
                    if (v > best) { best = v; bi = l; }
                }
                const int blankness = (bi == BLANK_) ? 1 : 0;
                int tiv = ti_l[g2] + blankness;
                if (tiv >= olen_s[g2]) {
                    ti_l[g2] = tiv;                      // frozen
                } else {
                    int notb = 1 - blankness;
                    int sav = blankness ? 0 : sa_l[g2];
                    int nl = last_l[g2];
                    int lcn = lc_l[g2];
                    if (notb) {
                        lcn += 1;
                        if (lb == g2) {                  // designated writer
                            int bglob = bb0 + g2;
                            if (lcn < NSTEPS_) st_i(&out[bglob*NSTEPS_ + lcn], bi);
                            st_i(&out[B_*NSTEPS_ + bglob], lcn);
                        }
                        nl = bi;
                        sav += 1;
                    }
                    if (sav >= MAXSYM_) { tiv += 1; sav = 0; }
                    ti_l[g2] = tiv; sa_l[g2] = sav; last_l[g2] = nl; lc_l[g2] = lcn;
                    nb = notb; act = 1;
                }
            }
            nb_a[tid] = nb; act_a[tid] = act;
        }
        __syncthreads();
        if (tid == 0) {
            unsigned m0 = 0, m1 = 0;
            for (int q = 0; q < GB; ++q) {
                m0 |= (unsigned)(nb_a[q] != 0) << q;
                m1 |= (unsigned)(act_a[q] != 0) << q;
            }
            s_masks[0] = m0; s_masks[1] = m1;
        }
        __syncthreads();
        const unsigned nbm_new = s_masks[0];
        actm = s_masks[1];
        // commit accepted candidates + speculative P0
        if (tid < 128) {
            int g2 = tid & 15;
            if ((nbm_new >> g2) & 1) { c0cur[tid] = c0cand[tid]; c1cur[tid] = c1cand[tid]; }
        }
        for (int i = tid; i < 32*GB; i += BDEC) {
            if ((nbm_new >> (i % GB)) & 1) P0a[i] = P0b[i];
        }
        __syncthreads();
        nbm = nbm_new;
        if (tid == 0) st_i(&tagD[lb*16], s + 1);
        if (!actm) break;
    }
}

extern "C" void kernel_launch(void* const* d_in, const int* in_sizes, int n_in,
                              void* d_out, int out_size, void* d_ws, size_t ws_size,
                              hipStream_t stream) {
    const float* x    = (const float*)d_in[0];
    const int*   olen = (const int*)d_in[1];
    const float* emb  = (const float*)d_in[2];
    const float* Wi0  = (const float*)d_in[3];
    const float* Wh0  = (const float*)d_in[4];
    const float* b0   = (const float*)d_in[5];
    const float* Wi1  = (const float*)d_in[6];
    const float* Wh1  = (const float*)d_in[7];
    const float* b1   = (const float*)d_in[8];
    const float* Wj1  = (const float*)d_in[9];
    const float* bj1  = (const float*)d_in[10];
    const float* Wj2  = (const float*)d_in[11];
    const float* bj2  = (const float*)d_in[12];
    float* ws = (float*)d_ws;
    int* out = (int*)d_out;

    hipLaunchKernelGGL(k_init, dim3(256), dim3(256), 0, stream, ws, out);
    hipLaunchKernelGGL(k_we,   dim3(28*5), dim3(256), 0, stream, emb, Wi0, ws);
    hipLaunchKernelGGL(k_fpre, dim3(T_*8), dim3(256), 0, stream, x, Wj1, bj1, ws);
    hipLaunchKernelGGL(k_decode, dim3(GDEC), dim3(BDEC), 0, stream,
                       olen, Wh0, b0, Wi1, Wh1, b1, Wj1, Wj2, bj2, ws, out);
}